// Round 8
// baseline (1256.667 us; speedup 1.0000x reference)
//
#include <hip/hip_runtime.h>
#include <hip/hip_bf16.h>
#include <math.h>
#include <stdint.h>

#define LSEQ 1024
#define DMODEL 768
#define DINNER 1536
#define DSTATE 16
#define DRANK 48
#define KCONV 4
#define NLAYER 2
#define DBC 80  // DRANK + 2*DSTATE

typedef unsigned short u16;
typedef __attribute__((ext_vector_type(8))) __bf16 bf16x8;
typedef __attribute__((ext_vector_type(4))) float f32x4;
typedef __attribute__((ext_vector_type(4))) unsigned short us4;

__device__ __forceinline__ u16 f2bf(float f) {
  union { float f; unsigned u; } v; v.f = f;
  unsigned r = v.u + 0x7fffu + ((v.u >> 16) & 1u);  // RNE
  return (u16)(r >> 16);
}

// CK-style addrspace casts for global_load_lds (direct HBM->LDS DMA, 16B/lane)
__device__ __forceinline__ void gload16(const void* g, void* l) {
  auto gp = reinterpret_cast<const __attribute__((address_space(1))) uint32_t*>(
      reinterpret_cast<uintptr_t>(g));
  auto lp = reinterpret_cast<__attribute__((address_space(3))) uint32_t*>(
      reinterpret_cast<uintptr_t>(l));
  __builtin_amdgcn_global_load_lds(gp, lp, 16, 0, 0);
}

// ---------------- fp32 -> bf16 flat convert ----------------
__global__ __launch_bounds__(256) void cvt_k(const float* __restrict__ in,
                                             u16* __restrict__ out, int n4) {
  int i = blockIdx.x * 256 + threadIdx.x;
  if (i >= n4) return;
  float4 v = ((const float4*)in)[i];
  us4 o; o[0] = f2bf(v.x); o[1] = f2bf(v.y); o[2] = f2bf(v.z); o[3] = f2bf(v.w);
  ((us4*)out)[i] = o;
}

// ---------------- fp32 -> bf16 transpose-convert ----------------
__global__ __launch_bounds__(256) void transcvt_k(const float* __restrict__ in,
                                                  u16* __restrict__ out,
                                                  int R, int C) {
  __shared__ float t[32][33];
  int c0 = blockIdx.x * 32, r0 = blockIdx.y * 32;
  int tx = threadIdx.x & 31, ty = threadIdx.x >> 5;
  for (int i = ty; i < 32; i += 8) t[i][tx] = in[(size_t)(r0 + i) * C + c0 + tx];
  __syncthreads();
  for (int i = ty; i < 32; i += 8)
    out[(size_t)(c0 + i) * R + r0 + tx] = f2bf(t[tx][i]);
}

// ---------------- bf16 -> bf16 transpose ----------------
__global__ __launch_bounds__(256) void transpose16_k(const u16* __restrict__ in,
                                                     u16* __restrict__ out,
                                                     int R, int C) {
  __shared__ u16 t[32][34];
  int c0 = blockIdx.x * 32, r0 = blockIdx.y * 32;
  int tx = threadIdx.x & 31, ty = threadIdx.x >> 5;
  for (int i = ty; i < 32; i += 8) t[i][tx] = in[(size_t)(r0 + i) * C + c0 + tx];
  __syncthreads();
  for (int i = ty; i < 32; i += 8)
    out[(size_t)(c0 + i) * R + r0 + tx] = t[tx][i];
}

// ---------------- rmsnorm (bf16 out) ----------------
__global__ __launch_bounds__(256) void rmsnorm_k(const float* __restrict__ x,
                                                 const float* __restrict__ w,
                                                 u16* __restrict__ xn) {
  int row = blockIdx.x;
  int tid = threadIdx.x;
  const float* xr = x + (size_t)row * DMODEL;
  float ss = 0.f;
  for (int j = tid; j < DMODEL; j += 256) { float v = xr[j]; ss += v * v; }
  __shared__ float red[256];
  red[tid] = ss; __syncthreads();
  for (int s = 128; s > 0; s >>= 1) { if (tid < s) red[tid] += red[tid + s]; __syncthreads(); }
  float scale = rsqrtf(red[0] / (float)DMODEL + 1e-5f);
  u16* outr = xn + (size_t)row * DMODEL;
  for (int j = tid; j < DMODEL; j += 256) outr[j] = f2bf(xr[j] * scale * w[j]);
}

// ---------------- MFMA bf16 GEMM: 64x64 tile, BK=64, occupancy-first --------
// C[m,n] = sum_k A[m,k]*B[n,k]; A [M,K] bf16, B [N,K] bf16 (NT).
// 4 waves, each 32x32 (2x2 frags of 16x16x32). Double-buffered LDS (32 KB).
// LDS chunk-XOR swizzle (r&7), pre-swizzled global source (rule #21).
// Bijective XCD swizzle on linear block id (all grids %8 == 0).
// EPI bit0: +bias[n]; bit2: +resid fp32; bit3: bf16 output.
template<int EPI>
__global__ __launch_bounds__(256) void mgemm_k(
    const u16* __restrict__ A, int lda,
    const u16* __restrict__ B, int ldb,
    void* __restrict__ Cv, int ldc, int K,
    const float* __restrict__ bias,
    const float* __restrict__ resid, int ldr)
{
  __shared__ u16 As[2][64 * 64];
  __shared__ u16 Bs[2][64 * 64];
  const int tid = threadIdx.x;
  const int lane = tid & 63;
  const int w = tid >> 6;

  const int nbx = gridDim.x;
  int bid = blockIdx.y * nbx + blockIdx.x;
  const int nwg = nbx * gridDim.y;
  bid = (bid & 7) * (nwg >> 3) + (bid >> 3);
  const int bm = (bid / nbx) * 64;
  const int bn = (bid % nbx) * 64;

  const int srow = lane >> 3;
  const int scs = (lane & 7) ^ srow;
  const int gA = 2 * w;
  const u16* Asrc0 = A + (size_t)(bm + gA * 8 + srow) * lda + scs * 8;
  const u16* Asrc1 = Asrc0 + (size_t)8 * lda;
  const u16* Bsrc0 = B + (size_t)(bn + gA * 8 + srow) * ldb + scs * 8;
  const u16* Bsrc1 = Bsrc0 + (size_t)8 * ldb;
  const int d0 = gA * 512;
  const int d1 = d0 + 512;

  const int fr = lane & 15;
  const int fs = lane >> 4;
  const int wm = (w >> 1) * 32;
  const int wn = (w & 1) * 32;
  int aoff[2][2], boff[2][2];
#pragma unroll
  for (int i = 0; i < 2; i++)
#pragma unroll
    for (int h = 0; h < 2; h++) {
      const int g = h * 4 + fs;
      aoff[i][h] = (wm + i * 16 + fr) * 64 + (g ^ (fr & 7)) * 8;
      boff[i][h] = (wn + i * 16 + fr) * 64 + (g ^ (fr & 7)) * 8;
    }

  f32x4 acc[2][2];
#pragma unroll
  for (int i = 0; i < 2; i++)
#pragma unroll
    for (int j = 0; j < 2; j++) acc[i][j] = (f32x4){0.f, 0.f, 0.f, 0.f};

#define STAGE(buf, k0) do { \
    gload16(Asrc0 + (k0), &As[buf][d0]); \
    gload16(Asrc1 + (k0), &As[buf][d1]); \
    gload16(Bsrc0 + (k0), &Bs[buf][d0]); \
    gload16(Bsrc1 + (k0), &Bs[buf][d1]); \
  } while (0)

  const int nk = K >> 6;
  STAGE(0, 0);

  for (int t = 0; t < nk; t++) {
    const int buf = t & 1;
    __syncthreads();
    if (t + 1 < nk) STAGE(buf ^ 1, (t + 1) << 6);
    const u16* As_ = As[buf];
    const u16* Bs_ = Bs[buf];
#pragma unroll
    for (int h = 0; h < 2; h++) {
      bf16x8 a0 = *reinterpret_cast<const bf16x8*>(As_ + aoff[0][h]);
      bf16x8 a1 = *reinterpret_cast<const bf16x8*>(As_ + aoff[1][h]);
      bf16x8 b0 = *reinterpret_cast<const bf16x8*>(Bs_ + boff[0][h]);
      bf16x8 b1 = *reinterpret_cast<const bf16x8*>(Bs_ + boff[1][h]);
      acc[0][0] = __builtin_amdgcn_mfma_f32_16x16x32_bf16(a0, b0, acc[0][0], 0, 0, 0);
      acc[0][1] = __builtin_amdgcn_mfma_f32_16x16x32_bf16(a0, b1, acc[0][1], 0, 0, 0);
      acc[1][0] = __builtin_amdgcn_mfma_f32_16x16x32_bf16(a1, b0, acc[1][0], 0, 0, 0);
      acc[1][1] = __builtin_amdgcn_mfma_f32_16x16x32_bf16(a1, b1, acc[1][1], 0, 0, 0);
    }
  }
#undef STAGE

#pragma unroll
  for (int i = 0; i < 2; i++) {
#pragma unroll
    for (int j = 0; j < 2; j++) {
      const int col = bn + wn + j * 16 + fr;
      const int row0 = bm + wm + i * 16 + fs * 4;
      float bv = (EPI & 1) ? bias[col] : 0.f;
#pragma unroll
      for (int r = 0; r < 4; r++) {
        float v = acc[i][j][r] + bv;
        if (EPI & 4) v += resid[(size_t)(row0 + r) * ldr + col];
        if (EPI & 8) ((u16*)Cv)[(size_t)(row0 + r) * ldc + col] = f2bf(v);
        else         ((float*)Cv)[(size_t)(row0 + r) * ldc + col] = v;
      }
    }
  }
}

// ---------------- thin dbc GEMM (f+b merged): partial[dir][ks][1024][80] -----
#define TG_R 16
#define TG_KC 96
#define TG_KS 16

__global__ __launch_bounds__(256) void thin_gemm_k(
    const float* __restrict__ Af_, const float* __restrict__ Ab_,
    const float* __restrict__ Bf_, const float* __restrict__ Bb_,
    float* __restrict__ partial)
{
  __shared__ float As[TG_R][100];
  __shared__ float Bs[80][100];
  const float* A = blockIdx.z ? Ab_ : Af_;
  const float* B = blockIdx.z ? Bb_ : Bf_;
  float* part = partial + (size_t)blockIdx.z * TG_KS * LSEQ * DBC;
  const int tid = threadIdx.x;
  const int m0 = blockIdx.x * TG_R;
  const int ks = blockIdx.y;
  const int k0 = ks * TG_KC;

  for (int i = tid; i < 384; i += 256) {
    int r = i / 24, q = i % 24;
    *(float4*)&As[r][q * 4] = *(const float4*)(A + (size_t)(m0 + r) * DINNER + k0 + q * 4);
  }
  for (int i = tid; i < 1920; i += 256) {
    int r = i / 24, q = i % 24;
    *(float4*)&Bs[r][q * 4] = *(const float4*)(B + (size_t)r * DINNER + k0 + q * 4);
  }
  __syncthreads();

  const int r = tid >> 4;
  const int c0 = (tid & 15) * 5;
  float acc[5] = {};
  for (int k = 0; k < TG_KC; k++) {
    float a = As[r][k];
#pragma unroll
    for (int j = 0; j < 5; j++) acc[j] += a * Bs[c0 + j][k];
  }
  float* out = part + ((size_t)ks * LSEQ + m0 + r) * DBC + c0;
#pragma unroll
  for (int j = 0; j < 5; j++) out[j] = acc[j];
}

__global__ __launch_bounds__(256) void reduce_dbc_k(const float* __restrict__ partial,
                                                    float* __restrict__ outf,
                                                    float* __restrict__ outb) {
  int i = blockIdx.x * 256 + threadIdx.x;
  const float* part = partial + (size_t)blockIdx.y * TG_KS * LSEQ * DBC;
  float s = 0.f;
#pragma unroll
  for (int ks = 0; ks < TG_KS; ks++) s += part[(size_t)ks * (LSEQ * DBC) + i];
  (blockIdx.y ? outb : outf)[i] = s;
}

// ---------------- delta = softplus(dlt @ dt_w^T + dt_b), f+b merged ----------
#define BM 64
#define BN 64
#define BK 16

__global__ __launch_bounds__(256) void delta_gemm_k(
    const float* __restrict__ A0, const float* __restrict__ A1,
    const float* __restrict__ B0, const float* __restrict__ B1,
    const float* __restrict__ b0, const float* __restrict__ b1,
    float* __restrict__ C0, float* __restrict__ C1)
{
  __shared__ float Asf[BK][BM];
  __shared__ float Bsf[BK][BN + 4];
  const float* A = blockIdx.z ? A1 : A0;
  const float* B = blockIdx.z ? B1 : B0;
  const float* bias = blockIdx.z ? b1 : b0;
  float* C = blockIdx.z ? C1 : C0;
  const int tid = threadIdx.x;
  const int bm = blockIdx.y * BM;
  const int bn = blockIdx.x * BN;
  const int ar = tid >> 2;
  const int ak = (tid & 3) << 2;
  const int ty = tid >> 4, tx = tid & 15;
  float acc[4][4] = {};

  for (int k0 = 0; k0 < DRANK; k0 += BK) {
    float4 av = *(const float4*)(A + (size_t)(bm + ar) * DBC + k0 + ak);
    float4 bv = *(const float4*)(B + (size_t)(bn + ar) * DRANK + k0 + ak);
    __syncthreads();
    Asf[ak + 0][ar] = av.x; Asf[ak + 1][ar] = av.y;
    Asf[ak + 2][ar] = av.z; Asf[ak + 3][ar] = av.w;
    Bsf[ak + 0][ar] = bv.x; Bsf[ak + 1][ar] = bv.y;
    Bsf[ak + 2][ar] = bv.z; Bsf[ak + 3][ar] = bv.w;
    __syncthreads();
#pragma unroll
    for (int kk = 0; kk < BK; kk++) {
      float4 a4 = *(const float4*)&Asf[kk][ty * 4];
      float4 b4 = *(const float4*)&Bsf[kk][tx * 4];
      float a[4] = {a4.x, a4.y, a4.z, a4.w};
      float b[4] = {b4.x, b4.y, b4.z, b4.w};
#pragma unroll
      for (int i = 0; i < 4; i++)
#pragma unroll
        for (int j = 0; j < 4; j++)
          acc[i][j] += a[i] * b[j];
    }
  }

#pragma unroll
  for (int i = 0; i < 4; i++) {
    int row = bm + ty * 4 + i;
#pragma unroll
    for (int j = 0; j < 4; j++) {
      int col = bn + tx * 4 + j;
      float v = acc[i][j] + bias[col];
      v = (v > 20.f) ? v : log1pf(__expf(v));
      C[(size_t)row * DINNER + col] = v;
    }
  }
}

// ---------------- causal depthwise conv + silu (both directions) -------------
__global__ __launch_bounds__(256) void conv_silu_k(
    const float* __restrict__ xz,
    const float* __restrict__ wf, const float* __restrict__ bf,
    const float* __restrict__ wb, const float* __restrict__ bb,
    float* __restrict__ xf, float* __restrict__ xb)
{
  int idx = blockIdx.x * 256 + threadIdx.x;
  int dir = blockIdx.y;
  if (idx >= LSEQ * DINNER) return;
  int l = idx / DINNER, c = idx % DINNER;
  const float* w = (dir ? wb : wf) + c * KCONV;
  float acc = (dir ? bb : bf)[c];
#pragma unroll
  for (int k = 0; k < KCONV; k++) {
    int ls = l - (KCONV - 1) + k;
    if (ls >= 0) {
      int lsrc = dir ? (LSEQ - 1 - ls) : ls;
      acc += w[k] * xz[(size_t)lsrc * (2 * DINNER) + c];
    }
  }
  float sv = acc / (1.f + __expf(-acc));
  (dir ? xb : xf)[idx] = sv;
}

// ---------------- state-parallel single-pass selective scan ------------------
// block = 16 channels x 16 states = 256 threads; each thread owns one (d,s)
// chain over the full L (serial dep = 1 FMA/step). y = sum_s h*C via 4x
// shfl_xor within the 16-lane s-group. Inputs read ONCE, full-cacheline
// (16 consecutive channels/block; s-lanes broadcast-read the same address).
// Output staged in a 16x16 LDS tile, flushed coalesced every 16 steps.
__global__ __launch_bounds__(256) void scan_k(
    const float* __restrict__ xcf, const float* __restrict__ xcb,
    const float* __restrict__ dltf, const float* __restrict__ dltb,
    const float* __restrict__ dbcf, const float* __restrict__ dbcb,
    const float* __restrict__ Af, const float* __restrict__ Ab,
    const float* __restrict__ Df, const float* __restrict__ Db,
    u16* __restrict__ ycat)
{
  __shared__ float ytile[16][16];
  const int dir = blockIdx.y;
  const float* xc    = dir ? xcb : xcf;
  const float* delta = dir ? dltb : dltf;
  const float* dbc   = dir ? dbcb : dbcf;
  const float* A_log = dir ? Ab : Af;
  const float* Dvec  = dir ? Db : Df;
  const int col_off  = dir ? DINNER : 0;

  const int tid = threadIdx.x;
  const int s  = tid & 15;          // state lane
  const int ch = tid >> 4;          // channel 0..15
  const int d  = blockIdx.x * 16 + ch;

  const float Aa = -__expf(A_log[(size_t)d * DSTATE + s]);
  const float Dd = Dvec[d];
  float h = 0.f;

  const int dcol = blockIdx.x * 16;
  for (int lt = 0; lt < LSEQ / 16; lt++) {
#pragma unroll
    for (int i = 0; i < 16; i++) {
      const int l = lt * 16 + i;
      float dt = delta[(size_t)l * DINNER + d];
      float xv = xc[(size_t)l * DINNER + d];
      float bm = dbc[(size_t)l * DBC + DRANK + s];
      float cm = dbc[(size_t)l * DBC + DRANK + DSTATE + s];
      float a = __expf(dt * Aa);
      h = a * h + (dt * xv) * bm;
      float yp = h * cm;
      yp += __shfl_xor(yp, 1);
      yp += __shfl_xor(yp, 2);
      yp += __shfl_xor(yp, 4);
      yp += __shfl_xor(yp, 8);
      if (s == 0) ytile[i][ch] = yp + Dd * xv;
    }
    __syncthreads();
    {
      const int r = tid >> 4, c2 = tid & 15;
      ycat[(size_t)(lt * 16 + r) * (2 * DINNER) + col_off + dcol + c2] =
          f2bf(ytile[r][c2]);
    }
    __syncthreads();
  }
}

// ---------------- row softmax (fp32 in, bf16 out) ----------------
__global__ __launch_bounds__(256) void softmax_k(const float* __restrict__ S,
                                                 u16* __restrict__ P) {
  int row = blockIdx.x, tid = threadIdx.x;
  __shared__ float buf[LSEQ];
  __shared__ float red[256];
  const float* r = S + (size_t)row * LSEQ;
  float m = -1e30f;
  for (int j = tid; j < LSEQ; j += 256) { float v = r[j]; buf[j] = v; m = fmaxf(m, v); }
  red[tid] = m; __syncthreads();
  for (int s = 128; s > 0; s >>= 1) { if (tid < s) red[tid] = fmaxf(red[tid], red[tid + s]); __syncthreads(); }
  m = red[0];
  __syncthreads();
  float sum = 0.f;
  for (int j = tid; j < LSEQ; j += 256) { float e = __expf(buf[j] - m); buf[j] = e; sum += e; }
  red[tid] = sum; __syncthreads();
  for (int s = 128; s > 0; s >>= 1) { if (tid < s) red[tid] += red[tid + s]; __syncthreads(); }
  float inv = 1.f / red[0];
  u16* pr = P + (size_t)row * LSEQ;
  for (int j = tid; j < LSEQ; j += 256) pr[j] = f2bf(buf[j] * inv);
}

// ---------------- g = y2 * silu(z) (bf16 out) ----------------
__global__ __launch_bounds__(256) void silumul_k(const float* __restrict__ y2,
                                                 const float* __restrict__ xz,
                                                 u16* __restrict__ g) {
  int idx = blockIdx.x * 256 + threadIdx.x;
  if (idx >= LSEQ * DINNER) return;
  int l = idx / DINNER, d = idx % DINNER;
  float z = xz[(size_t)l * (2 * DINNER) + DINNER + d];
  float s = z / (1.f + __expf(-z));
  g[idx] = f2bf(y2[idx] * s);
}

extern "C" void kernel_launch(void* const* d_in, const int* in_sizes, int n_in,
                              void* d_out, int out_size, void* d_ws, size_t ws_size,
                              hipStream_t stream) {
  const float* in_x      = (const float*)d_in[0];
  const float* norm_w    = (const float*)d_in[1];
  const float* in_proj_w = (const float*)d_in[2];
  const float* conv_f_w  = (const float*)d_in[3];
  const float* conv_f_b  = (const float*)d_in[4];
  const float* conv_b_w  = (const float*)d_in[5];
  const float* conv_b_b  = (const float*)d_in[6];
  const float* xproj_f_w = (const float*)d_in[7];
  const float* xproj_b_w = (const float*)d_in[8];
  const float* dt_f_w    = (const float*)d_in[9];
  const float* dt_f_b    = (const float*)d_in[10];
  const float* dt_b_w    = (const float*)d_in[11];
  const float* dt_b_b    = (const float*)d_in[12];
  const float* A_log_f   = (const float*)d_in[13];
  const float* D_f       = (const float*)d_in[14];
  const float* A_log_b   = (const float*)d_in[15];
  const float* D_b       = (const float*)d_in[16];
  const float* out_w     = (const float*)d_in[17];
  const float* token_wA  = (const float*)d_in[18];
  const float* token_wV  = (const float*)d_in[19];
  const float* pro_w     = (const float*)d_in[20];
  const float* pro_b     = (const float*)d_in[21];

  // ---- workspace carve (fp32 units) ----
  float* ws = (float*)d_ws;
  float* xbuf = ws; ws += LSEQ * DMODEL;
  float* xz   = ws; ws += LSEQ * 2 * DINNER;
  float* xf   = ws; ws += LSEQ * DINNER;
  float* xb   = ws; ws += LSEQ * DINNER;
  float* dbcf = ws; ws += LSEQ * DBC;
  float* dbcb = ws; ws += LSEQ * DBC;
  float* delf = ws; ws += LSEQ * DINNER;   // +delb: dbc partials pre-delta; Smat post-scan
  float* delb = ws; ws += LSEQ * DINNER;
  float* y2   = ws; ws += LSEQ * DINNER;
  u16* xn_bf   = (u16*)ws; ws += (LSEQ * DMODEL) / 2;
  u16* ycat_bf = (u16*)ws; ws += LSEQ * DINNER;
  u16* ypro_bf = (u16*)ws; ws += (LSEQ * DINNER) / 2;
  u16* Wb      = (u16*)ws;
  u16* in_w_bf = Wb;
  u16* pw_bf   = in_w_bf + 3072 * 768;
  u16* wA_bf   = pw_bf + 1536 * 3072;
  u16* wVT_bf  = wA_bf + 1024 * 1536;
  u16* ow_bf   = wVT_bf + 1536 * 1536;

  // aliases (verified live ranges)
  float* dbc_part = delf;       // [2][16][1024][80] = 2.62M fl <= delf+delb (3.1M, contiguous)
  float* Smat    = delf;        // written after scans consume delf
  u16*   Smat_bf = (u16*)delb;
  u16*   vv_bf   = (u16*)xf;    // xf dead after scan
  u16*   vvT_bf  = (u16*)xb;    // xb dead after scan
  u16*   g_bf    = ypro_bf;     // ypro last read by vv gemm

  hipMemcpyAsync(xbuf, in_x, sizeof(float) * LSEQ * DMODEL,
                 hipMemcpyDeviceToDevice, stream);

  dim3 blk(256);
  for (int layer = 0; layer < NLAYER; layer++) {
    const float* nw  = norm_w    + (size_t)layer * DMODEL;
    const float* iw  = in_proj_w + (size_t)layer * 2 * DINNER * DMODEL;
    const float* cfw = conv_f_w  + (size_t)layer * DINNER * KCONV;
    const float* cfb = conv_f_b  + (size_t)layer * DINNER;
    const float* cbw = conv_b_w  + (size_t)layer * DINNER * KCONV;
    const float* cbb = conv_b_b  + (size_t)layer * DINNER;
    const float* xfw = xproj_f_w + (size_t)layer * DBC * DINNER;
    const float* xbw = xproj_b_w + (size_t)layer * DBC * DINNER;
    const float* dfw = dt_f_w    + (size_t)layer * DINNER * DRANK;
    const float* dfb = dt_f_b    + (size_t)layer * DINNER;
    const float* dbw = dt_b_w    + (size_t)layer * DINNER * DRANK;
    const float* dbb = dt_b_b    + (size_t)layer * DINNER;
    const float* Af  = A_log_f   + (size_t)layer * DINNER * DSTATE;
    const float* Df  = D_f       + (size_t)layer * DINNER;
    const float* Ab  = A_log_b   + (size_t)layer * DINNER * DSTATE;
    const float* Db  = D_b       + (size_t)layer * DINNER;
    const float* ow  = out_w     + (size_t)layer * DMODEL * DINNER;
    const float* wA  = token_wA  + (size_t)layer * LSEQ * DINNER;
    const float* wV  = token_wV  + (size_t)layer * DINNER * DINNER;
    const float* pw  = pro_w     + (size_t)layer * DINNER * 2 * DINNER;
    const float* pb  = pro_b     + (size_t)layer * DINNER;

    // weight conversions for this layer
    cvt_k<<<(3072 * 768 / 4 + 255) / 256, blk, 0, stream>>>(iw, in_w_bf, 3072 * 768 / 4);
    cvt_k<<<(1536 * 3072 / 4 + 255) / 256, blk, 0, stream>>>(pw, pw_bf, 1536 * 3072 / 4);
    cvt_k<<<(1024 * 1536 / 4 + 255) / 256, blk, 0, stream>>>(wA, wA_bf, 1024 * 1536 / 4);
    cvt_k<<<(768 * 1536 / 4 + 255) / 256, blk, 0, stream>>>(ow, ow_bf, 768 * 1536 / 4);
    transcvt_k<<<dim3(1536 / 32, 1536 / 32), blk, 0, stream>>>(wV, wVT_bf, 1536, 1536);

    rmsnorm_k<<<LSEQ, blk, 0, stream>>>(xbuf, nw, xn_bf);

    // xz = xn @ in_w^T   [1024,3072] k=768   (grid 768)
    mgemm_k<0><<<dim3(3072 / 64, LSEQ / 64), blk, 0, stream>>>(
        xn_bf, DMODEL, in_w_bf, DMODEL, xz, 2 * DINNER, DMODEL, nullptr, nullptr, 0);

    conv_silu_k<<<dim3((LSEQ * DINNER) / 256, 2), blk, 0, stream>>>(
        xz, cfw, cfb, cbw, cbb, xf, xb);

    // dbc = x @ xproj^T  [1024,80] k=1536 (f+b merged K-split thin GEMM)
    thin_gemm_k<<<dim3(LSEQ / TG_R, TG_KS, 2), blk, 0, stream>>>(
        xf, xb, xfw, xbw, dbc_part);
    reduce_dbc_k<<<dim3((LSEQ * DBC) / 256, 2), blk, 0, stream>>>(
        dbc_part, dbcf, dbcb);

    // delta = softplus(dlt @ dt_w^T + dt_b)  [1024,1536] k=48 (f+b merged)
    delta_gemm_k<<<dim3(DINNER / BN, LSEQ / BM, 2), blk, 0, stream>>>(
        dbcf, dbcb, dfw, dbw, dfb, dbb, delf, delb);

    // state-parallel scans (f+b merged), grid (96, 2)
    scan_k<<<dim3(DINNER / 16, 2), blk, 0, stream>>>(
        xf, xb, delf, delb, dbcf, dbcb, Af, Ab, Df, Db, ycat_bf);

    // ypro = ycat @ pro_w^T + pro_b   [1024,1536] k=3072 -> bf16  (grid 384)
    mgemm_k<9><<<dim3(DINNER / 64, LSEQ / 64), blk, 0, stream>>>(
        ycat_bf, 2 * DINNER, pw_bf, 2 * DINNER, ypro_bf, DINNER, 2 * DINNER,
        pb, nullptr, 0);

    // S = wA . ypro^T   [1024,1024] k=1536 -> fp32  (grid 256)
    mgemm_k<0><<<dim3(LSEQ / 64, LSEQ / 64), blk, 0, stream>>>(
        wA_bf, DINNER, ypro_bf, DINNER, Smat, LSEQ, DINNER, nullptr, nullptr, 0);
    softmax_k<<<LSEQ, blk, 0, stream>>>(Smat, Smat_bf);

    // vv = ypro @ wV    [1024,1536] k=1536 -> bf16 (B = wV^T)  (grid 384)
    mgemm_k<8><<<dim3(DINNER / 64, LSEQ / 64), blk, 0, stream>>>(
        ypro_bf, DINNER, wVT_bf, DINNER, vv_bf, DINNER, DINNER, nullptr, nullptr, 0);

    // vvT[e][l] = vv[l][e]
    transpose16_k<<<dim3(DINNER / 32, LSEQ / 32), blk, 0, stream>>>(
        vv_bf, vvT_bf, LSEQ, DINNER);

    // y2 = att @ vv     [1024,1536] k=1024 -> fp32 (B = vv^T)  (grid 384)
    mgemm_k<0><<<dim3(DINNER / 64, LSEQ / 64), blk, 0, stream>>>(
        Smat_bf, LSEQ, vvT_bf, LSEQ, y2, DINNER, LSEQ, nullptr, nullptr, 0);

    silumul_k<<<(LSEQ * DINNER) / 256, blk, 0, stream>>>(y2, xz, g_bf);

    // x_next = x + g @ out_w^T   [1024,768] k=1536  (grid 192)
    float* target = (layer == NLAYER - 1) ? (float*)d_out : xbuf;
    mgemm_k<4><<<dim3(DMODEL / 64, LSEQ / 64), blk, 0, stream>>>(
        g_bf, DINNER, ow_bf, DINNER, target, DMODEL, DINNER,
        nullptr, xbuf, DMODEL);
  }
}

// Round 9
// 540.479 us; speedup vs baseline: 2.3251x; 2.3251x over previous
//
#include <hip/hip_runtime.h>
#include <hip/hip_bf16.h>
#include <math.h>
#include <stdint.h>

#define LSEQ 1024
#define DMODEL 768
#define DINNER 1536
#define DSTATE 16
#define DRANK 48
#define KCONV 4
#define NLAYER 2
#define DBC 80  // DRANK + 2*DSTATE

typedef unsigned short u16;
typedef __attribute__((ext_vector_type(8))) __bf16 bf16x8;
typedef __attribute__((ext_vector_type(4))) float f32x4;
typedef __attribute__((ext_vector_type(4))) unsigned short us4;

__device__ __forceinline__ u16 f2bf(float f) {
  union { float f; unsigned u; } v; v.f = f;
  unsigned r = v.u + 0x7fffu + ((v.u >> 16) & 1u);  // RNE
  return (u16)(r >> 16);
}

// CK-style addrspace casts for global_load_lds (direct HBM->LDS DMA, 16B/lane)
__device__ __forceinline__ void gload16(const void* g, void* l) {
  auto gp = reinterpret_cast<const __attribute__((address_space(1))) uint32_t*>(
      reinterpret_cast<uintptr_t>(g));
  auto lp = reinterpret_cast<__attribute__((address_space(3))) uint32_t*>(
      reinterpret_cast<uintptr_t>(l));
  __builtin_amdgcn_global_load_lds(gp, lp, 16, 0, 0);
}

// ---------------- fp32 -> bf16 flat convert ----------------
__global__ __launch_bounds__(256) void cvt_k(const float* __restrict__ in,
                                             u16* __restrict__ out, int n4) {
  int i = blockIdx.x * 256 + threadIdx.x;
  if (i >= n4) return;
  float4 v = ((const float4*)in)[i];
  us4 o; o[0] = f2bf(v.x); o[1] = f2bf(v.y); o[2] = f2bf(v.z); o[3] = f2bf(v.w);
  ((us4*)out)[i] = o;
}

// ---------------- fp32 -> bf16 transpose-convert ----------------
__global__ __launch_bounds__(256) void transcvt_k(const float* __restrict__ in,
                                                  u16* __restrict__ out,
                                                  int R, int C) {
  __shared__ float t[32][33];
  int c0 = blockIdx.x * 32, r0 = blockIdx.y * 32;
  int tx = threadIdx.x & 31, ty = threadIdx.x >> 5;
  for (int i = ty; i < 32; i += 8) t[i][tx] = in[(size_t)(r0 + i) * C + c0 + tx];
  __syncthreads();
  for (int i = ty; i < 32; i += 8)
    out[(size_t)(c0 + i) * R + r0 + tx] = f2bf(t[tx][i]);
}

// ---------------- bf16 -> bf16 transpose ----------------
__global__ __launch_bounds__(256) void transpose16_k(const u16* __restrict__ in,
                                                     u16* __restrict__ out,
                                                     int R, int C) {
  __shared__ u16 t[32][34];
  int c0 = blockIdx.x * 32, r0 = blockIdx.y * 32;
  int tx = threadIdx.x & 31, ty = threadIdx.x >> 5;
  for (int i = ty; i < 32; i += 8) t[i][tx] = in[(size_t)(r0 + i) * C + c0 + tx];
  __syncthreads();
  for (int i = ty; i < 32; i += 8)
    out[(size_t)(c0 + i) * R + r0 + tx] = t[tx][i];
}

// ---------------- rmsnorm (bf16 out) ----------------
__global__ __launch_bounds__(256) void rmsnorm_k(const float* __restrict__ x,
                                                 const float* __restrict__ w,
                                                 u16* __restrict__ xn) {
  int row = blockIdx.x;
  int tid = threadIdx.x;
  const float* xr = x + (size_t)row * DMODEL;
  float ss = 0.f;
  for (int j = tid; j < DMODEL; j += 256) { float v = xr[j]; ss += v * v; }
  __shared__ float red[256];
  red[tid] = ss; __syncthreads();
  for (int s = 128; s > 0; s >>= 1) { if (tid < s) red[tid] += red[tid + s]; __syncthreads(); }
  float scale = rsqrtf(red[0] / (float)DMODEL + 1e-5f);
  u16* outr = xn + (size_t)row * DMODEL;
  for (int j = tid; j < DMODEL; j += 256) outr[j] = f2bf(xr[j] * scale * w[j]);
}

// ---------------- MFMA bf16 GEMM: 64x64 tile, BK=64, occupancy-first --------
// (unchanged from round 7 — proven)
template<int EPI>
__global__ __launch_bounds__(256) void mgemm_k(
    const u16* __restrict__ A, int lda,
    const u16* __restrict__ B, int ldb,
    void* __restrict__ Cv, int ldc, int K,
    const float* __restrict__ bias,
    const float* __restrict__ resid, int ldr)
{
  __shared__ u16 As[2][64 * 64];
  __shared__ u16 Bs[2][64 * 64];
  const int tid = threadIdx.x;
  const int lane = tid & 63;
  const int w = tid >> 6;

  const int nbx = gridDim.x;
  int bid = blockIdx.y * nbx + blockIdx.x;
  const int nwg = nbx * gridDim.y;
  bid = (bid & 7) * (nwg >> 3) + (bid >> 3);
  const int bm = (bid / nbx) * 64;
  const int bn = (bid % nbx) * 64;

  const int srow = lane >> 3;
  const int scs = (lane & 7) ^ srow;
  const int gA = 2 * w;
  const u16* Asrc0 = A + (size_t)(bm + gA * 8 + srow) * lda + scs * 8;
  const u16* Asrc1 = Asrc0 + (size_t)8 * lda;
  const u16* Bsrc0 = B + (size_t)(bn + gA * 8 + srow) * ldb + scs * 8;
  const u16* Bsrc1 = Bsrc0 + (size_t)8 * ldb;
  const int d0 = gA * 512;
  const int d1 = d0 + 512;

  const int fr = lane & 15;
  const int fs = lane >> 4;
  const int wm = (w >> 1) * 32;
  const int wn = (w & 1) * 32;
  int aoff[2][2], boff[2][2];
#pragma unroll
  for (int i = 0; i < 2; i++)
#pragma unroll
    for (int h = 0; h < 2; h++) {
      const int g = h * 4 + fs;
      aoff[i][h] = (wm + i * 16 + fr) * 64 + (g ^ (fr & 7)) * 8;
      boff[i][h] = (wn + i * 16 + fr) * 64 + (g ^ (fr & 7)) * 8;
    }

  f32x4 acc[2][2];
#pragma unroll
  for (int i = 0; i < 2; i++)
#pragma unroll
    for (int j = 0; j < 2; j++) acc[i][j] = (f32x4){0.f, 0.f, 0.f, 0.f};

#define STAGE(buf, k0) do { \
    gload16(Asrc0 + (k0), &As[buf][d0]); \
    gload16(Asrc1 + (k0), &As[buf][d1]); \
    gload16(Bsrc0 + (k0), &Bs[buf][d0]); \
    gload16(Bsrc1 + (k0), &Bs[buf][d1]); \
  } while (0)

  const int nk = K >> 6;
  STAGE(0, 0);

  for (int t = 0; t < nk; t++) {
    const int buf = t & 1;
    __syncthreads();
    if (t + 1 < nk) STAGE(buf ^ 1, (t + 1) << 6);
    const u16* As_ = As[buf];
    const u16* Bs_ = Bs[buf];
#pragma unroll
    for (int h = 0; h < 2; h++) {
      bf16x8 a0 = *reinterpret_cast<const bf16x8*>(As_ + aoff[0][h]);
      bf16x8 a1 = *reinterpret_cast<const bf16x8*>(As_ + aoff[1][h]);
      bf16x8 b0 = *reinterpret_cast<const bf16x8*>(Bs_ + boff[0][h]);
      bf16x8 b1 = *reinterpret_cast<const bf16x8*>(Bs_ + boff[1][h]);
      acc[0][0] = __builtin_amdgcn_mfma_f32_16x16x32_bf16(a0, b0, acc[0][0], 0, 0, 0);
      acc[0][1] = __builtin_amdgcn_mfma_f32_16x16x32_bf16(a0, b1, acc[0][1], 0, 0, 0);
      acc[1][0] = __builtin_amdgcn_mfma_f32_16x16x32_bf16(a1, b0, acc[1][0], 0, 0, 0);
      acc[1][1] = __builtin_amdgcn_mfma_f32_16x16x32_bf16(a1, b1, acc[1][1], 0, 0, 0);
    }
  }
#undef STAGE

#pragma unroll
  for (int i = 0; i < 2; i++) {
#pragma unroll
    for (int j = 0; j < 2; j++) {
      const int col = bn + wn + j * 16 + fr;
      const int row0 = bm + wm + i * 16 + fs * 4;
      float bv = (EPI & 1) ? bias[col] : 0.f;
#pragma unroll
      for (int r = 0; r < 4; r++) {
        float v = acc[i][j][r] + bv;
        if (EPI & 4) v += resid[(size_t)(row0 + r) * ldr + col];
        if (EPI & 8) ((u16*)Cv)[(size_t)(row0 + r) * ldc + col] = f2bf(v);
        else         ((float*)Cv)[(size_t)(row0 + r) * ldc + col] = v;
      }
    }
  }
}

// ---------------- thin dbc GEMM (f+b merged): partial[dir][ks][1024][80] -----
#define TG_R 16
#define TG_KC 96
#define TG_KS 16

__global__ __launch_bounds__(256) void thin_gemm_k(
    const float* __restrict__ Af_, const float* __restrict__ Ab_,
    const float* __restrict__ Bf_, const float* __restrict__ Bb_,
    float* __restrict__ partial)
{
  __shared__ float As[TG_R][100];
  __shared__ float Bs[80][100];
  const float* A = blockIdx.z ? Ab_ : Af_;
  const float* B = blockIdx.z ? Bb_ : Bf_;
  float* part = partial + (size_t)blockIdx.z * TG_KS * LSEQ * DBC;
  const int tid = threadIdx.x;
  const int m0 = blockIdx.x * TG_R;
  const int ks = blockIdx.y;
  const int k0 = ks * TG_KC;

  for (int i = tid; i < 384; i += 256) {
    int r = i / 24, q = i % 24;
    *(float4*)&As[r][q * 4] = *(const float4*)(A + (size_t)(m0 + r) * DINNER + k0 + q * 4);
  }
  for (int i = tid; i < 1920; i += 256) {
    int r = i / 24, q = i % 24;
    *(float4*)&Bs[r][q * 4] = *(const float4*)(B + (size_t)r * DINNER + k0 + q * 4);
  }
  __syncthreads();

  const int r = tid >> 4;
  const int c0 = (tid & 15) * 5;
  float acc[5] = {};
  for (int k = 0; k < TG_KC; k++) {
    float a = As[r][k];
#pragma unroll
    for (int j = 0; j < 5; j++) acc[j] += a * Bs[c0 + j][k];
  }
  float* out = part + ((size_t)ks * LSEQ + m0 + r) * DBC + c0;
#pragma unroll
  for (int j = 0; j < 5; j++) out[j] = acc[j];
}

__global__ __launch_bounds__(256) void reduce_dbc_k(const float* __restrict__ partial,
                                                    float* __restrict__ outf,
                                                    float* __restrict__ outb) {
  int i = blockIdx.x * 256 + threadIdx.x;
  const float* part = partial + (size_t)blockIdx.y * TG_KS * LSEQ * DBC;
  float s = 0.f;
#pragma unroll
  for (int ks = 0; ks < TG_KS; ks++) s += part[(size_t)ks * (LSEQ * DBC) + i];
  (blockIdx.y ? outb : outf)[i] = s;
}

// ---------------- delta = softplus(dlt @ dt_w^T + dt_b), f+b merged ----------
#define BM 64
#define BN 64
#define BK 16

__global__ __launch_bounds__(256) void delta_gemm_k(
    const float* __restrict__ A0, const float* __restrict__ A1,
    const float* __restrict__ B0, const float* __restrict__ B1,
    const float* __restrict__ b0, const float* __restrict__ b1,
    float* __restrict__ C0, float* __restrict__ C1)
{
  __shared__ float Asf[BK][BM];
  __shared__ float Bsf[BK][BN + 4];
  const float* A = blockIdx.z ? A1 : A0;
  const float* B = blockIdx.z ? B1 : B0;
  const float* bias = blockIdx.z ? b1 : b0;
  float* C = blockIdx.z ? C1 : C0;
  const int tid = threadIdx.x;
  const int bm = blockIdx.y * BM;
  const int bn = blockIdx.x * BN;
  const int ar = tid >> 2;
  const int ak = (tid & 3) << 2;
  const int ty = tid >> 4, tx = tid & 15;
  float acc[4][4] = {};

  for (int k0 = 0; k0 < DRANK; k0 += BK) {
    float4 av = *(const float4*)(A + (size_t)(bm + ar) * DBC + k0 + ak);
    float4 bv = *(const float4*)(B + (size_t)(bn + ar) * DRANK + k0 + ak);
    __syncthreads();
    Asf[ak + 0][ar] = av.x; Asf[ak + 1][ar] = av.y;
    Asf[ak + 2][ar] = av.z; Asf[ak + 3][ar] = av.w;
    Bsf[ak + 0][ar] = bv.x; Bsf[ak + 1][ar] = bv.y;
    Bsf[ak + 2][ar] = bv.z; Bsf[ak + 3][ar] = bv.w;
    __syncthreads();
#pragma unroll
    for (int kk = 0; kk < BK; kk++) {
      float4 a4 = *(const float4*)&Asf[kk][ty * 4];
      float4 b4 = *(const float4*)&Bsf[kk][tx * 4];
      float a[4] = {a4.x, a4.y, a4.z, a4.w};
      float b[4] = {b4.x, b4.y, b4.z, b4.w};
#pragma unroll
      for (int i = 0; i < 4; i++)
#pragma unroll
        for (int j = 0; j < 4; j++)
          acc[i][j] += a[i] * b[j];
    }
  }

#pragma unroll
  for (int i = 0; i < 4; i++) {
    int row = bm + ty * 4 + i;
#pragma unroll
    for (int j = 0; j < 4; j++) {
      int col = bn + tx * 4 + j;
      float v = acc[i][j] + bias[col];
      v = (v > 20.f) ? v : log1pf(__expf(v));
      C[(size_t)row * DINNER + col] = v;
    }
  }
}

// ---------------- causal depthwise conv + silu (both directions) -------------
__global__ __launch_bounds__(256) void conv_silu_k(
    const float* __restrict__ xz,
    const float* __restrict__ wf, const float* __restrict__ bf,
    const float* __restrict__ wb, const float* __restrict__ bb,
    float* __restrict__ xf, float* __restrict__ xb)
{
  int idx = blockIdx.x * 256 + threadIdx.x;
  int dir = blockIdx.y;
  if (idx >= LSEQ * DINNER) return;
  int l = idx / DINNER, c = idx % DINNER;
  const float* w = (dir ? wb : wf) + c * KCONV;
  float acc = (dir ? bb : bf)[c];
#pragma unroll
  for (int k = 0; k < KCONV; k++) {
    int ls = l - (KCONV - 1) + k;
    if (ls >= 0) {
      int lsrc = dir ? (LSEQ - 1 - ls) : ls;
      acc += w[k] * xz[(size_t)lsrc * (2 * DINNER) + c];
    }
  }
  float sv = acc / (1.f + __expf(-acc));
  (dir ? xb : xf)[idx] = sv;
}

// ---------------- chunked selective scan (round-5 shape, f+b merged) ---------
// block = 256 = 16 chunks x 16 CONSECUTIVE channels (full 64B-line reads);
// 16 independent state chains per thread (ILP). 2 passes; phase-3 re-reads
// are L2-resident (~256 KB/block). grid (DINNER/16, 2).
__global__ __launch_bounds__(256) void scan_k(
    const float* __restrict__ xcf, const float* __restrict__ xcb,
    const float* __restrict__ dltf, const float* __restrict__ dltb,
    const float* __restrict__ dbcf, const float* __restrict__ dbcb,
    const float* __restrict__ Af, const float* __restrict__ Ab,
    const float* __restrict__ Df, const float* __restrict__ Db,
    u16* __restrict__ ycat)
{
  __shared__ float sP[16 * 16 * 16];
  __shared__ float sQ[16 * 16 * 16];
  const int dir = blockIdx.y;
  const float* xc    = dir ? xcb : xcf;
  const float* delta = dir ? dltb : dltf;
  const float* dbc   = dir ? dbcb : dbcf;
  const float* A_log = dir ? Ab : Af;
  const float* Dvec  = dir ? Db : Df;
  const int col_off  = dir ? DINNER : 0;

  const int tid = threadIdx.x;
  const int c = tid >> 4;       // chunk 0..15
  const int dl = tid & 15;      // channel-local (consecutive -> coalesced)
  const int d = blockIdx.x * 16 + dl;
  const int CH = LSEQ / 16;     // 64

  float Aa[DSTATE];
#pragma unroll
  for (int s = 0; s < DSTATE; s++) Aa[s] = -__expf(A_log[(size_t)d * DSTATE + s]);

  // phase 1: per-chunk affine summary (16 independent chains -> ILP)
  float aP[DSTATE], q[DSTATE];
#pragma unroll
  for (int s = 0; s < DSTATE; s++) { aP[s] = 1.f; q[s] = 0.f; }
  const int l0 = c * CH;
  for (int i = 0; i < CH; i++) {
    int l = l0 + i;
    float dt = delta[(size_t)l * DINNER + d];
    float dx = dt * xc[(size_t)l * DINNER + d];
    const float* bm = dbc + (size_t)l * DBC + DRANK;
#pragma unroll
    for (int s = 0; s < DSTATE; s++) {
      float a = __expf(dt * Aa[s]);
      q[s] = a * q[s] + dx * bm[s];
      aP[s] *= a;
    }
  }
#pragma unroll
  for (int s = 0; s < DSTATE; s++) {
    sP[(c * 16 + dl) * 16 + s] = aP[s];
    sQ[(c * 16 + dl) * 16 + s] = q[s];
  }
  __syncthreads();

  // phase 2: serial combine across 16 chunks (all 256 threads: one (ch,s) each)
  {
    const int d2 = tid >> 4, s2 = tid & 15;
    float h = 0.f;
    for (int cc = 0; cc < 16; cc++) {
      int idx = (cc * 16 + d2) * 16 + s2;
      float a = sP[idx], qq = sQ[idx];
      sP[idx] = h;
      h = a * h + qq;
    }
  }
  __syncthreads();

  // phase 3: replay with carry-in, emit y (reads are L2 hits)
  float hs[DSTATE];
#pragma unroll
  for (int s = 0; s < DSTATE; s++) hs[s] = sP[(c * 16 + dl) * 16 + s];
  const float Dd = Dvec[d];
  for (int i = 0; i < CH; i++) {
    int l = l0 + i;
    float dt = delta[(size_t)l * DINNER + d];
    float xv = xc[(size_t)l * DINNER + d];
    float dx = dt * xv;
    const float* bm = dbc + (size_t)l * DBC + DRANK;
    const float* cm = bm + DSTATE;
    float y = 0.f;
#pragma unroll
    for (int s = 0; s < DSTATE; s++) {
      float a = __expf(dt * Aa[s]);
      hs[s] = a * hs[s] + dx * bm[s];
      y += hs[s] * cm[s];
    }
    ycat[(size_t)l * (2 * DINNER) + col_off + d] = f2bf(y + Dd * xv);
  }
}

// ---------------- row softmax (fp32 in, bf16 out) ----------------
__global__ __launch_bounds__(256) void softmax_k(const float* __restrict__ S,
                                                 u16* __restrict__ P) {
  int row = blockIdx.x, tid = threadIdx.x;
  __shared__ float buf[LSEQ];
  __shared__ float red[256];
  const float* r = S + (size_t)row * LSEQ;
  float m = -1e30f;
  for (int j = tid; j < LSEQ; j += 256) { float v = r[j]; buf[j] = v; m = fmaxf(m, v); }
  red[tid] = m; __syncthreads();
  for (int s = 128; s > 0; s >>= 1) { if (tid < s) red[tid] = fmaxf(red[tid], red[tid + s]); __syncthreads(); }
  m = red[0];
  __syncthreads();
  float sum = 0.f;
  for (int j = tid; j < LSEQ; j += 256) { float e = __expf(buf[j] - m); buf[j] = e; sum += e; }
  red[tid] = sum; __syncthreads();
  for (int s = 128; s > 0; s >>= 1) { if (tid < s) red[tid] += red[tid + s]; __syncthreads(); }
  float inv = 1.f / red[0];
  u16* pr = P + (size_t)row * LSEQ;
  for (int j = tid; j < LSEQ; j += 256) pr[j] = f2bf(buf[j] * inv);
}

// ---------------- g = y2 * silu(z) (bf16 out) ----------------
__global__ __launch_bounds__(256) void silumul_k(const float* __restrict__ y2,
                                                 const float* __restrict__ xz,
                                                 u16* __restrict__ g) {
  int idx = blockIdx.x * 256 + threadIdx.x;
  if (idx >= LSEQ * DINNER) return;
  int l = idx / DINNER, d = idx % DINNER;
  float z = xz[(size_t)l * (2 * DINNER) + DINNER + d];
  float s = z / (1.f + __expf(-z));
  g[idx] = f2bf(y2[idx] * s);
}

extern "C" void kernel_launch(void* const* d_in, const int* in_sizes, int n_in,
                              void* d_out, int out_size, void* d_ws, size_t ws_size,
                              hipStream_t stream) {
  const float* in_x      = (const float*)d_in[0];
  const float* norm_w    = (const float*)d_in[1];
  const float* in_proj_w = (const float*)d_in[2];
  const float* conv_f_w  = (const float*)d_in[3];
  const float* conv_f_b  = (const float*)d_in[4];
  const float* conv_b_w  = (const float*)d_in[5];
  const float* conv_b_b  = (const float*)d_in[6];
  const float* xproj_f_w = (const float*)d_in[7];
  const float* xproj_b_w = (const float*)d_in[8];
  const float* dt_f_w    = (const float*)d_in[9];
  const float* dt_f_b    = (const float*)d_in[10];
  const float* dt_b_w    = (const float*)d_in[11];
  const float* dt_b_b    = (const float*)d_in[12];
  const float* A_log_f   = (const float*)d_in[13];
  const float* D_f       = (const float*)d_in[14];
  const float* A_log_b   = (const float*)d_in[15];
  const float* D_b       = (const float*)d_in[16];
  const float* out_w     = (const float*)d_in[17];
  const float* token_wA  = (const float*)d_in[18];
  const float* token_wV  = (const float*)d_in[19];
  const float* pro_w     = (const float*)d_in[20];
  const float* pro_b     = (const float*)d_in[21];

  // ---- workspace carve (fp32 units) ----
  float* ws = (float*)d_ws;
  float* xbuf = ws; ws += LSEQ * DMODEL;
  float* xz   = ws; ws += LSEQ * 2 * DINNER;
  float* xf   = ws; ws += LSEQ * DINNER;
  float* xb   = ws; ws += LSEQ * DINNER;
  float* dbcf = ws; ws += LSEQ * DBC;
  float* dbcb = ws; ws += LSEQ * DBC;
  float* delf = ws; ws += LSEQ * DINNER;   // +delb: dbc partials pre-delta; Smat post-scan
  float* delb = ws; ws += LSEQ * DINNER;
  float* y2   = ws; ws += LSEQ * DINNER;
  u16* xn_bf   = (u16*)ws; ws += (LSEQ * DMODEL) / 2;
  u16* ycat_bf = (u16*)ws; ws += LSEQ * DINNER;
  u16* ypro_bf = (u16*)ws; ws += (LSEQ * DINNER) / 2;
  u16* Wb      = (u16*)ws;
  u16* in_w_bf = Wb;
  u16* pw_bf   = in_w_bf + 3072 * 768;
  u16* wA_bf   = pw_bf + 1536 * 3072;
  u16* wVT_bf  = wA_bf + 1024 * 1536;
  u16* ow_bf   = wVT_bf + 1536 * 1536;

  // aliases (verified live ranges)
  float* dbc_part = delf;       // [2][16][1024][80] = 2.62M fl <= delf+delb (3.1M, contiguous)
  float* Smat    = delf;        // written after scans consume delf
  u16*   Smat_bf = (u16*)delb;
  u16*   vv_bf   = (u16*)xf;    // xf dead after scan
  u16*   vvT_bf  = (u16*)xb;    // xb dead after scan
  u16*   g_bf    = ypro_bf;     // ypro last read by vv gemm

  hipMemcpyAsync(xbuf, in_x, sizeof(float) * LSEQ * DMODEL,
                 hipMemcpyDeviceToDevice, stream);

  dim3 blk(256);
  for (int layer = 0; layer < NLAYER; layer++) {
    const float* nw  = norm_w    + (size_t)layer * DMODEL;
    const float* iw  = in_proj_w + (size_t)layer * 2 * DINNER * DMODEL;
    const float* cfw = conv_f_w  + (size_t)layer * DINNER * KCONV;
    const float* cfb = conv_f_b  + (size_t)layer * DINNER;
    const float* cbw = conv_b_w  + (size_t)layer * DINNER * KCONV;
    const float* cbb = conv_b_b  + (size_t)layer * DINNER;
    const float* xfw = xproj_f_w + (size_t)layer * DBC * DINNER;
    const float* xbw = xproj_b_w + (size_t)layer * DBC * DINNER;
    const float* dfw = dt_f_w    + (size_t)layer * DINNER * DRANK;
    const float* dfb = dt_f_b    + (size_t)layer * DINNER;
    const float* dbw = dt_b_w    + (size_t)layer * DINNER * DRANK;
    const float* dbb = dt_b_b    + (size_t)layer * DINNER;
    const float* Af  = A_log_f   + (size_t)layer * DINNER * DSTATE;
    const float* Df  = D_f       + (size_t)layer * DINNER;
    const float* Ab  = A_log_b   + (size_t)layer * DINNER * DSTATE;
    const float* Db  = D_b       + (size_t)layer * DINNER;
    const float* ow  = out_w     + (size_t)layer * DMODEL * DINNER;
    const float* wA  = token_wA  + (size_t)layer * LSEQ * DINNER;
    const float* wV  = token_wV  + (size_t)layer * DINNER * DINNER;
    const float* pw  = pro_w     + (size_t)layer * DINNER * 2 * DINNER;
    const float* pb  = pro_b     + (size_t)layer * DINNER;

    // weight conversions for this layer
    cvt_k<<<(3072 * 768 / 4 + 255) / 256, blk, 0, stream>>>(iw, in_w_bf, 3072 * 768 / 4);
    cvt_k<<<(1536 * 3072 / 4 + 255) / 256, blk, 0, stream>>>(pw, pw_bf, 1536 * 3072 / 4);
    cvt_k<<<(1024 * 1536 / 4 + 255) / 256, blk, 0, stream>>>(wA, wA_bf, 1024 * 1536 / 4);
    cvt_k<<<(768 * 1536 / 4 + 255) / 256, blk, 0, stream>>>(ow, ow_bf, 768 * 1536 / 4);
    transcvt_k<<<dim3(1536 / 32, 1536 / 32), blk, 0, stream>>>(wV, wVT_bf, 1536, 1536);

    rmsnorm_k<<<LSEQ, blk, 0, stream>>>(xbuf, nw, xn_bf);

    // xz = xn @ in_w^T   [1024,3072] k=768   (grid 768)
    mgemm_k<0><<<dim3(3072 / 64, LSEQ / 64), blk, 0, stream>>>(
        xn_bf, DMODEL, in_w_bf, DMODEL, xz, 2 * DINNER, DMODEL, nullptr, nullptr, 0);

    conv_silu_k<<<dim3((LSEQ * DINNER) / 256, 2), blk, 0, stream>>>(
        xz, cfw, cfb, cbw, cbb, xf, xb);

    // dbc = x @ xproj^T  [1024,80] k=1536 (f+b merged K-split thin GEMM)
    thin_gemm_k<<<dim3(LSEQ / TG_R, TG_KS, 2), blk, 0, stream>>>(
        xf, xb, xfw, xbw, dbc_part);
    reduce_dbc_k<<<dim3((LSEQ * DBC) / 256, 2), blk, 0, stream>>>(
        dbc_part, dbcf, dbcb);

    // delta = softplus(dlt @ dt_w^T + dt_b)  [1024,1536] k=48 (f+b merged)
    delta_gemm_k<<<dim3(DINNER / BN, LSEQ / BM, 2), blk, 0, stream>>>(
        dbcf, dbcb, dfw, dbw, dfb, dbb, delf, delb);

    // chunked scans (f+b merged), grid (96, 2)
    scan_k<<<dim3(DINNER / 16, 2), blk, 0, stream>>>(
        xf, xb, delf, delb, dbcf, dbcb, Af, Ab, Df, Db, ycat_bf);

    // ypro = ycat @ pro_w^T + pro_b   [1024,1536] k=3072 -> bf16  (grid 384)
    mgemm_k<9><<<dim3(DINNER / 64, LSEQ / 64), blk, 0, stream>>>(
        ycat_bf, 2 * DINNER, pw_bf, 2 * DINNER, ypro_bf, DINNER, 2 * DINNER,
        pb, nullptr, 0);

    // S = wA . ypro^T   [1024,1024] k=1536 -> fp32  (grid 256)
    mgemm_k<0><<<dim3(LSEQ / 64, LSEQ / 64), blk, 0, stream>>>(
        wA_bf, DINNER, ypro_bf, DINNER, Smat, LSEQ, DINNER, nullptr, nullptr, 0);
    softmax_k<<<LSEQ, blk, 0, stream>>>(Smat, Smat_bf);

    // vv = ypro @ wV    [1024,1536] k=1536 -> bf16 (B = wV^T)  (grid 384)
    mgemm_k<8><<<dim3(DINNER / 64, LSEQ / 64), blk, 0, stream>>>(
        ypro_bf, DINNER, wVT_bf, DINNER, vv_bf, DINNER, DINNER, nullptr, nullptr, 0);

    // vvT[e][l] = vv[l][e]
    transpose16_k<<<dim3(DINNER / 32, LSEQ / 32), blk, 0, stream>>>(
        vv_bf, vvT_bf, LSEQ, DINNER);

    // y2 = att @ vv     [1024,1536] k=1024 -> fp32 (B = vv^T)  (grid 384)
    mgemm_k<0><<<dim3(DINNER / 64, LSEQ / 64), blk, 0, stream>>>(
        Smat_bf, LSEQ, vvT_bf, LSEQ, y2, DINNER, LSEQ, nullptr, nullptr, 0);

    silumul_k<<<(LSEQ * DINNER) / 256, blk, 0, stream>>>(y2, xz, g_bf);

    // x_next = x + g @ out_w^T   [1024,768] k=1536  (grid 192)
    float* target = (layer == NLAYER - 1) ? (float*)d_out : xbuf;
    mgemm_k<4><<<dim3(DMODEL / 64, LSEQ / 64), blk, 0, stream>>>(
        g_bf, DINNER, ow_bf, DINNER, target, DMODEL, DINNER,
        nullptr, xbuf, DMODEL);
  }
}

// Round 10
// 459.637 us; speedup vs baseline: 2.7340x; 1.1759x over previous
//
#include <hip/hip_runtime.h>
#include <hip/hip_bf16.h>
#include <math.h>
#include <stdint.h>

#define LSEQ 1024
#define DMODEL 768
#define DINNER 1536
#define DSTATE 16
#define DRANK 48
#define KCONV 4
#define NLAYER 2
#define DBC 80  // DRANK + 2*DSTATE
#define NQ 4            // L quarters for the 3-phase scan
#define QL (LSEQ / NQ)  // 256
#define QCH (QL / 16)   // 16 steps per chunk

typedef unsigned short u16;
typedef __attribute__((ext_vector_type(8))) __bf16 bf16x8;
typedef __attribute__((ext_vector_type(4))) float f32x4;
typedef __attribute__((ext_vector_type(4))) unsigned short us4;

__device__ __forceinline__ u16 f2bf(float f) {
  union { float f; unsigned u; } v; v.f = f;
  unsigned r = v.u + 0x7fffu + ((v.u >> 16) & 1u);  // RNE
  return (u16)(r >> 16);
}

// CK-style addrspace casts for global_load_lds (direct HBM->LDS DMA, 16B/lane)
__device__ __forceinline__ void gload16(const void* g, void* l) {
  auto gp = reinterpret_cast<const __attribute__((address_space(1))) uint32_t*>(
      reinterpret_cast<uintptr_t>(g));
  auto lp = reinterpret_cast<__attribute__((address_space(3))) uint32_t*>(
      reinterpret_cast<uintptr_t>(l));
  __builtin_amdgcn_global_load_lds(gp, lp, 16, 0, 0);
}

// ---------------- fp32 -> bf16 flat convert ----------------
__global__ __launch_bounds__(256) void cvt_k(const float* __restrict__ in,
                                             u16* __restrict__ out, int n4) {
  int i = blockIdx.x * 256 + threadIdx.x;
  if (i >= n4) return;
  float4 v = ((const float4*)in)[i];
  us4 o; o[0] = f2bf(v.x); o[1] = f2bf(v.y); o[2] = f2bf(v.z); o[3] = f2bf(v.w);
  ((us4*)out)[i] = o;
}

// ---------------- fp32 -> bf16 transpose-convert ----------------
__global__ __launch_bounds__(256) void transcvt_k(const float* __restrict__ in,
                                                  u16* __restrict__ out,
                                                  int R, int C) {
  __shared__ float t[32][33];
  int c0 = blockIdx.x * 32, r0 = blockIdx.y * 32;
  int tx = threadIdx.x & 31, ty = threadIdx.x >> 5;
  for (int i = ty; i < 32; i += 8) t[i][tx] = in[(size_t)(r0 + i) * C + c0 + tx];
  __syncthreads();
  for (int i = ty; i < 32; i += 8)
    out[(size_t)(c0 + i) * R + r0 + tx] = f2bf(t[tx][i]);
}

// ---------------- bf16 -> bf16 transpose ----------------
__global__ __launch_bounds__(256) void transpose16_k(const u16* __restrict__ in,
                                                     u16* __restrict__ out,
                                                     int R, int C) {
  __shared__ u16 t[32][34];
  int c0 = blockIdx.x * 32, r0 = blockIdx.y * 32;
  int tx = threadIdx.x & 31, ty = threadIdx.x >> 5;
  for (int i = ty; i < 32; i += 8) t[i][tx] = in[(size_t)(r0 + i) * C + c0 + tx];
  __syncthreads();
  for (int i = ty; i < 32; i += 8)
    out[(size_t)(c0 + i) * R + r0 + tx] = t[tx][i];
}

// ---------------- rmsnorm (bf16 out) ----------------
__global__ __launch_bounds__(256) void rmsnorm_k(const float* __restrict__ x,
                                                 const float* __restrict__ w,
                                                 u16* __restrict__ xn) {
  int row = blockIdx.x;
  int tid = threadIdx.x;
  const float* xr = x + (size_t)row * DMODEL;
  float ss = 0.f;
  for (int j = tid; j < DMODEL; j += 256) { float v = xr[j]; ss += v * v; }
  __shared__ float red[256];
  red[tid] = ss; __syncthreads();
  for (int s = 128; s > 0; s >>= 1) { if (tid < s) red[tid] += red[tid + s]; __syncthreads(); }
  float scale = rsqrtf(red[0] / (float)DMODEL + 1e-5f);
  u16* outr = xn + (size_t)row * DMODEL;
  for (int j = tid; j < DMODEL; j += 256) outr[j] = f2bf(xr[j] * scale * w[j]);
}

// ---------------- MFMA bf16 GEMM: 64x64 tile, BK=64, occupancy-first --------
// EPI bit0: +bias[n]; bit2: +resid fp32; bit3: bf16 output; bit4: *silu(resid).
template<int EPI>
__global__ __launch_bounds__(256) void mgemm_k(
    const u16* __restrict__ A, int lda,
    const u16* __restrict__ B, int ldb,
    void* __restrict__ Cv, int ldc, int K,
    const float* __restrict__ bias,
    const float* __restrict__ resid, int ldr)
{
  __shared__ u16 As[2][64 * 64];
  __shared__ u16 Bs[2][64 * 64];
  const int tid = threadIdx.x;
  const int lane = tid & 63;
  const int w = tid >> 6;

  const int nbx = gridDim.x;
  int bid = blockIdx.y * nbx + blockIdx.x;
  const int nwg = nbx * gridDim.y;
  bid = (bid & 7) * (nwg >> 3) + (bid >> 3);
  const int bm = (bid / nbx) * 64;
  const int bn = (bid % nbx) * 64;

  const int srow = lane >> 3;
  const int scs = (lane & 7) ^ srow;
  const int gA = 2 * w;
  const u16* Asrc0 = A + (size_t)(bm + gA * 8 + srow) * lda + scs * 8;
  const u16* Asrc1 = Asrc0 + (size_t)8 * lda;
  const u16* Bsrc0 = B + (size_t)(bn + gA * 8 + srow) * ldb + scs * 8;
  const u16* Bsrc1 = Bsrc0 + (size_t)8 * ldb;
  const int d0 = gA * 512;
  const int d1 = d0 + 512;

  const int fr = lane & 15;
  const int fs = lane >> 4;
  const int wm = (w >> 1) * 32;
  const int wn = (w & 1) * 32;
  int aoff[2][2], boff[2][2];
#pragma unroll
  for (int i = 0; i < 2; i++)
#pragma unroll
    for (int h = 0; h < 2; h++) {
      const int g = h * 4 + fs;
      aoff[i][h] = (wm + i * 16 + fr) * 64 + (g ^ (fr & 7)) * 8;
      boff[i][h] = (wn + i * 16 + fr) * 64 + (g ^ (fr & 7)) * 8;
    }

  f32x4 acc[2][2];
#pragma unroll
  for (int i = 0; i < 2; i++)
#pragma unroll
    for (int j = 0; j < 2; j++) acc[i][j] = (f32x4){0.f, 0.f, 0.f, 0.f};

#define STAGE(buf, k0) do { \
    gload16(Asrc0 + (k0), &As[buf][d0]); \
    gload16(Asrc1 + (k0), &As[buf][d1]); \
    gload16(Bsrc0 + (k0), &Bs[buf][d0]); \
    gload16(Bsrc1 + (k0), &Bs[buf][d1]); \
  } while (0)

  const int nk = K >> 6;
  STAGE(0, 0);

  for (int t = 0; t < nk; t++) {
    const int buf = t & 1;
    __syncthreads();
    if (t + 1 < nk) STAGE(buf ^ 1, (t + 1) << 6);
    const u16* As_ = As[buf];
    const u16* Bs_ = Bs[buf];
#pragma unroll
    for (int h = 0; h < 2; h++) {
      bf16x8 a0 = *reinterpret_cast<const bf16x8*>(As_ + aoff[0][h]);
      bf16x8 a1 = *reinterpret_cast<const bf16x8*>(As_ + aoff[1][h]);
      bf16x8 b0 = *reinterpret_cast<const bf16x8*>(Bs_ + boff[0][h]);
      bf16x8 b1 = *reinterpret_cast<const bf16x8*>(Bs_ + boff[1][h]);
      acc[0][0] = __builtin_amdgcn_mfma_f32_16x16x32_bf16(a0, b0, acc[0][0], 0, 0, 0);
      acc[0][1] = __builtin_amdgcn_mfma_f32_16x16x32_bf16(a0, b1, acc[0][1], 0, 0, 0);
      acc[1][0] = __builtin_amdgcn_mfma_f32_16x16x32_bf16(a1, b0, acc[1][0], 0, 0, 0);
      acc[1][1] = __builtin_amdgcn_mfma_f32_16x16x32_bf16(a1, b1, acc[1][1], 0, 0, 0);
    }
  }
#undef STAGE

#pragma unroll
  for (int i = 0; i < 2; i++) {
#pragma unroll
    for (int j = 0; j < 2; j++) {
      const int col = bn + wn + j * 16 + fr;
      const int row0 = bm + wm + i * 16 + fs * 4;
      float bv = (EPI & 1) ? bias[col] : 0.f;
#pragma unroll
      for (int r = 0; r < 4; r++) {
        float v = acc[i][j][r] + bv;
        if (EPI & 4) v += resid[(size_t)(row0 + r) * ldr + col];
        if (EPI & 16) {
          float z = resid[(size_t)(row0 + r) * ldr + col];
          v *= z / (1.f + __expf(-z));
        }
        if (EPI & 8) ((u16*)Cv)[(size_t)(row0 + r) * ldc + col] = f2bf(v);
        else         ((float*)Cv)[(size_t)(row0 + r) * ldc + col] = v;
      }
    }
  }
}

// ---------------- thin dbc GEMM (f+b merged): partial[dir][ks][1024][80] -----
#define TG_R 16
#define TG_KC 96
#define TG_KS 16

__global__ __launch_bounds__(256) void thin_gemm_k(
    const float* __restrict__ Af_, const float* __restrict__ Ab_,
    const float* __restrict__ Bf_, const float* __restrict__ Bb_,
    float* __restrict__ partial)
{
  __shared__ float As[TG_R][100];
  __shared__ float Bs[80][100];
  const float* A = blockIdx.z ? Ab_ : Af_;
  const float* B = blockIdx.z ? Bb_ : Bf_;
  float* part = partial + (size_t)blockIdx.z * TG_KS * LSEQ * DBC;
  const int tid = threadIdx.x;
  const int m0 = blockIdx.x * TG_R;
  const int ks = blockIdx.y;
  const int k0 = ks * TG_KC;

  for (int i = tid; i < 384; i += 256) {
    int r = i / 24, q = i % 24;
    *(float4*)&As[r][q * 4] = *(const float4*)(A + (size_t)(m0 + r) * DINNER + k0 + q * 4);
  }
  for (int i = tid; i < 1920; i += 256) {
    int r = i / 24, q = i % 24;
    *(float4*)&Bs[r][q * 4] = *(const float4*)(B + (size_t)r * DINNER + k0 + q * 4);
  }
  __syncthreads();

  const int r = tid >> 4;
  const int c0 = (tid & 15) * 5;
  float acc[5] = {};
  for (int k = 0; k < TG_KC; k++) {
    float a = As[r][k];
#pragma unroll
    for (int j = 0; j < 5; j++) acc[j] += a * Bs[c0 + j][k];
  }
  float* out = part + ((size_t)ks * LSEQ + m0 + r) * DBC + c0;
#pragma unroll
  for (int j = 0; j < 5; j++) out[j] = acc[j];
}

__global__ __launch_bounds__(256) void reduce_dbc_k(const float* __restrict__ partial,
                                                    float* __restrict__ outf,
                                                    float* __restrict__ outb) {
  int i = blockIdx.x * 256 + threadIdx.x;
  const float* part = partial + (size_t)blockIdx.y * TG_KS * LSEQ * DBC;
  float s = 0.f;
#pragma unroll
  for (int ks = 0; ks < TG_KS; ks++) s += part[(size_t)ks * (LSEQ * DBC) + i];
  (blockIdx.y ? outb : outf)[i] = s;
}

// ---------------- delta = softplus(dlt @ dt_w^T + dt_b), f+b merged ----------
#define BM 64
#define BN 64
#define BK 16

__global__ __launch_bounds__(256) void delta_gemm_k(
    const float* __restrict__ A0, const float* __restrict__ A1,
    const float* __restrict__ B0, const float* __restrict__ B1,
    const float* __restrict__ b0, const float* __restrict__ b1,
    float* __restrict__ C0, float* __restrict__ C1)
{
  __shared__ float Asf[BK][BM];
  __shared__ float Bsf[BK][BN + 4];
  const float* A = blockIdx.z ? A1 : A0;
  const float* B = blockIdx.z ? B1 : B0;
  const float* bias = blockIdx.z ? b1 : b0;
  float* C = blockIdx.z ? C1 : C0;
  const int tid = threadIdx.x;
  const int bm = blockIdx.y * BM;
  const int bn = blockIdx.x * BN;
  const int ar = tid >> 2;
  const int ak = (tid & 3) << 2;
  const int ty = tid >> 4, tx = tid & 15;
  float acc[4][4] = {};

  for (int k0 = 0; k0 < DRANK; k0 += BK) {
    float4 av = *(const float4*)(A + (size_t)(bm + ar) * DBC + k0 + ak);
    float4 bv = *(const float4*)(B + (size_t)(bn + ar) * DRANK + k0 + ak);
    __syncthreads();
    Asf[ak + 0][ar] = av.x; Asf[ak + 1][ar] = av.y;
    Asf[ak + 2][ar] = av.z; Asf[ak + 3][ar] = av.w;
    Bsf[ak + 0][ar] = bv.x; Bsf[ak + 1][ar] = bv.y;
    Bsf[ak + 2][ar] = bv.z; Bsf[ak + 3][ar] = bv.w;
    __syncthreads();
#pragma unroll
    for (int kk = 0; kk < BK; kk++) {
      float4 a4 = *(const float4*)&Asf[kk][ty * 4];
      float4 b4 = *(const float4*)&Bsf[kk][tx * 4];
      float a[4] = {a4.x, a4.y, a4.z, a4.w};
      float b[4] = {b4.x, b4.y, b4.z, b4.w};
#pragma unroll
      for (int i = 0; i < 4; i++)
#pragma unroll
        for (int j = 0; j < 4; j++)
          acc[i][j] += a[i] * b[j];
    }
  }

#pragma unroll
  for (int i = 0; i < 4; i++) {
    int row = bm + ty * 4 + i;
#pragma unroll
    for (int j = 0; j < 4; j++) {
      int col = bn + tx * 4 + j;
      float v = acc[i][j] + bias[col];
      v = (v > 20.f) ? v : log1pf(__expf(v));
      C[(size_t)row * DINNER + col] = v;
    }
  }
}

// ---------------- causal depthwise conv + silu (both directions) -------------
__global__ __launch_bounds__(256) void conv_silu_k(
    const float* __restrict__ xz,
    const float* __restrict__ wf, const float* __restrict__ bf,
    const float* __restrict__ wb, const float* __restrict__ bb,
    float* __restrict__ xf, float* __restrict__ xb)
{
  int idx = blockIdx.x * 256 + threadIdx.x;
  int dir = blockIdx.y;
  if (idx >= LSEQ * DINNER) return;
  int l = idx / DINNER, c = idx % DINNER;
  const float* w = (dir ? wb : wf) + c * KCONV;
  float acc = (dir ? bb : bf)[c];
#pragma unroll
  for (int k = 0; k < KCONV; k++) {
    int ls = l - (KCONV - 1) + k;
    if (ls >= 0) {
      int lsrc = dir ? (LSEQ - 1 - ls) : ls;
      acc += w[k] * xz[(size_t)lsrc * (2 * DINNER) + c];
    }
  }
  float sv = acc / (1.f + __expf(-acc));
  (dir ? xb : xf)[idx] = sv;
}

// ---------------- 3-phase L-split scan ----------------------------------------
// Recurrence h_t = a_t h_{t-1} + b_t over L=1024, split into NQ=4 quarters.
// A: per (ch-grp, quarter, dir) block: quarter summary (P, Q) per (d,s).
// B: combine quarters -> per-quarter carry h0.
// C: local scan with carry-in + emit y. grid A/C = (96, 4, 2) = 768 blocks.

__global__ __launch_bounds__(256) void scan_a_k(
    const float* __restrict__ xcf, const float* __restrict__ xcb,
    const float* __restrict__ dltf, const float* __restrict__ dltb,
    const float* __restrict__ dbcf, const float* __restrict__ dbcb,
    const float* __restrict__ Af, const float* __restrict__ Ab,
    float* __restrict__ qsP, float* __restrict__ qsQ)  // [2][NQ][DINNER][16]
{
  __shared__ float sP[16 * 16 * 16];
  __shared__ float sQ[16 * 16 * 16];
  const int dir = blockIdx.z;
  const int qid = blockIdx.y;
  const float* xc    = dir ? xcb : xcf;
  const float* delta = dir ? dltb : dltf;
  const float* dbc   = dir ? dbcb : dbcf;
  const float* A_log = dir ? Ab : Af;

  const int tid = threadIdx.x;
  const int c = tid >> 4;
  const int dl = tid & 15;
  const int d = blockIdx.x * 16 + dl;

  float Aa[DSTATE];
#pragma unroll
  for (int s = 0; s < DSTATE; s++) Aa[s] = -__expf(A_log[(size_t)d * DSTATE + s]);

  float aP[DSTATE], q[DSTATE];
#pragma unroll
  for (int s = 0; s < DSTATE; s++) { aP[s] = 1.f; q[s] = 0.f; }
  const int l0 = qid * QL + c * QCH;
  for (int i = 0; i < QCH; i++) {
    int l = l0 + i;
    float dt = delta[(size_t)l * DINNER + d];
    float dx = dt * xc[(size_t)l * DINNER + d];
    const float* bm = dbc + (size_t)l * DBC + DRANK;
#pragma unroll
    for (int s = 0; s < DSTATE; s++) {
      float a = __expf(dt * Aa[s]);
      q[s] = a * q[s] + dx * bm[s];
      aP[s] *= a;
    }
  }
#pragma unroll
  for (int s = 0; s < DSTATE; s++) {
    sP[(c * 16 + dl) * 16 + s] = aP[s];
    sQ[(c * 16 + dl) * 16 + s] = q[s];
  }
  __syncthreads();

  {  // phase 2: serial over 16 chunks; thread = (d2, s2)
    const int d2 = tid >> 4, s2 = tid & 15;
    float h = 0.f, P = 1.f;
    for (int cc = 0; cc < 16; cc++) {
      int idx = (cc * 16 + d2) * 16 + s2;
      float a = sP[idx];
      h = a * h + sQ[idx];
      P *= a;
    }
    size_t o = (((size_t)dir * NQ + qid) * DINNER + blockIdx.x * 16 + d2) * 16 + s2;
    qsP[o] = P;
    qsQ[o] = h;
  }
}

__global__ __launch_bounds__(256) void scan_b_k(const float* __restrict__ qsP,
                                                const float* __restrict__ qsQ,
                                                float* __restrict__ carry) {
  int i = blockIdx.x * 256 + threadIdx.x;      // over 2*DINNER*16 = 49152
  int dir = i / (DINNER * DSTATE);
  int rem = i % (DINNER * DSTATE);
  float h = 0.f;
#pragma unroll
  for (int q = 0; q < NQ; q++) {
    size_t o = ((size_t)dir * NQ + q) * (DINNER * DSTATE) + rem;
    carry[o] = h;
    h = qsP[o] * h + qsQ[o];
  }
}

__global__ __launch_bounds__(256) void scan_c_k(
    const float* __restrict__ xcf, const float* __restrict__ xcb,
    const float* __restrict__ dltf, const float* __restrict__ dltb,
    const float* __restrict__ dbcf, const float* __restrict__ dbcb,
    const float* __restrict__ Af, const float* __restrict__ Ab,
    const float* __restrict__ Df, const float* __restrict__ Db,
    const float* __restrict__ carry,
    u16* __restrict__ ycat)
{
  __shared__ float sP[16 * 16 * 16];
  __shared__ float sQ[16 * 16 * 16];
  const int dir = blockIdx.z;
  const int qid = blockIdx.y;
  const float* xc    = dir ? xcb : xcf;
  const float* delta = dir ? dltb : dltf;
  const float* dbc   = dir ? dbcb : dbcf;
  const float* A_log = dir ? Ab : Af;
  const float* Dvec  = dir ? Db : Df;
  const int col_off  = dir ? DINNER : 0;

  const int tid = threadIdx.x;
  const int c = tid >> 4;
  const int dl = tid & 15;
  const int d = blockIdx.x * 16 + dl;

  float Aa[DSTATE];
#pragma unroll
  for (int s = 0; s < DSTATE; s++) Aa[s] = -__expf(A_log[(size_t)d * DSTATE + s]);

  float aP[DSTATE], q[DSTATE];
#pragma unroll
  for (int s = 0; s < DSTATE; s++) { aP[s] = 1.f; q[s] = 0.f; }
  const int l0 = qid * QL + c * QCH;
  for (int i = 0; i < QCH; i++) {
    int l = l0 + i;
    float dt = delta[(size_t)l * DINNER + d];
    float dx = dt * xc[(size_t)l * DINNER + d];
    const float* bm = dbc + (size_t)l * DBC + DRANK;
#pragma unroll
    for (int s = 0; s < DSTATE; s++) {
      float a = __expf(dt * Aa[s]);
      q[s] = a * q[s] + dx * bm[s];
      aP[s] *= a;
    }
  }
#pragma unroll
  for (int s = 0; s < DSTATE; s++) {
    sP[(c * 16 + dl) * 16 + s] = aP[s];
    sQ[(c * 16 + dl) * 16 + s] = q[s];
  }
  __syncthreads();

  {  // phase 2 with quarter carry-in
    const int d2 = tid >> 4, s2 = tid & 15;
    float h = carry[(((size_t)dir * NQ + qid) * DINNER + blockIdx.x * 16 + d2) * 16 + s2];
    for (int cc = 0; cc < 16; cc++) {
      int idx = (cc * 16 + d2) * 16 + s2;
      float a = sP[idx], qq = sQ[idx];
      sP[idx] = h;
      h = a * h + qq;
    }
  }
  __syncthreads();

  float hs[DSTATE];
#pragma unroll
  for (int s = 0; s < DSTATE; s++) hs[s] = sP[(c * 16 + dl) * 16 + s];
  const float Dd = Dvec[d];
  for (int i = 0; i < QCH; i++) {
    int l = l0 + i;
    float dt = delta[(size_t)l * DINNER + d];
    float xv = xc[(size_t)l * DINNER + d];
    float dx = dt * xv;
    const float* bm = dbc + (size_t)l * DBC + DRANK;
    const float* cm = bm + DSTATE;
    float y = 0.f;
#pragma unroll
    for (int s = 0; s < DSTATE; s++) {
      float a = __expf(dt * Aa[s]);
      hs[s] = a * hs[s] + dx * bm[s];
      y += hs[s] * cm[s];
    }
    ycat[(size_t)l * (2 * DINNER) + col_off + d] = f2bf(y + Dd * xv);
  }
}

// ---------------- row softmax (fp32 in, bf16 out) ----------------
__global__ __launch_bounds__(256) void softmax_k(const float* __restrict__ S,
                                                 u16* __restrict__ P) {
  int row = blockIdx.x, tid = threadIdx.x;
  __shared__ float buf[LSEQ];
  __shared__ float red[256];
  const float* r = S + (size_t)row * LSEQ;
  float m = -1e30f;
  for (int j = tid; j < LSEQ; j += 256) { float v = r[j]; buf[j] = v; m = fmaxf(m, v); }
  red[tid] = m; __syncthreads();
  for (int s = 128; s > 0; s >>= 1) { if (tid < s) red[tid] = fmaxf(red[tid], red[tid + s]); __syncthreads(); }
  m = red[0];
  __syncthreads();
  float sum = 0.f;
  for (int j = tid; j < LSEQ; j += 256) { float e = __expf(buf[j] - m); buf[j] = e; sum += e; }
  red[tid] = sum; __syncthreads();
  for (int s = 128; s > 0; s >>= 1) { if (tid < s) red[tid] += red[tid + s]; __syncthreads(); }
  float inv = 1.f / red[0];
  u16* pr = P + (size_t)row * LSEQ;
  for (int j = tid; j < LSEQ; j += 256) pr[j] = f2bf(buf[j] * inv);
}

extern "C" void kernel_launch(void* const* d_in, const int* in_sizes, int n_in,
                              void* d_out, int out_size, void* d_ws, size_t ws_size,
                              hipStream_t stream) {
  const float* in_x      = (const float*)d_in[0];
  const float* norm_w    = (const float*)d_in[1];
  const float* in_proj_w = (const float*)d_in[2];
  const float* conv_f_w  = (const float*)d_in[3];
  const float* conv_f_b  = (const float*)d_in[4];
  const float* conv_b_w  = (const float*)d_in[5];
  const float* conv_b_b  = (const float*)d_in[6];
  const float* xproj_f_w = (const float*)d_in[7];
  const float* xproj_b_w = (const float*)d_in[8];
  const float* dt_f_w    = (const float*)d_in[9];
  const float* dt_f_b    = (const float*)d_in[10];
  const float* dt_b_w    = (const float*)d_in[11];
  const float* dt_b_b    = (const float*)d_in[12];
  const float* A_log_f   = (const float*)d_in[13];
  const float* D_f       = (const float*)d_in[14];
  const float* A_log_b   = (const float*)d_in[15];
  const float* D_b       = (const float*)d_in[16];
  const float* out_w     = (const float*)d_in[17];
  const float* token_wA  = (const float*)d_in[18];
  const float* token_wV  = (const float*)d_in[19];
  const float* pro_w     = (const float*)d_in[20];
  const float* pro_b     = (const float*)d_in[21];

  // ---- workspace carve (fp32 units) ----
  float* ws = (float*)d_ws;
  float* xbuf = ws; ws += LSEQ * DMODEL;
  float* xz   = ws; ws += LSEQ * 2 * DINNER;
  float* xf   = ws; ws += LSEQ * DINNER;
  float* xb   = ws; ws += LSEQ * DINNER;
  float* dbcf = ws; ws += LSEQ * DBC;
  float* dbcb = ws; ws += LSEQ * DBC;
  float* delf = ws; ws += LSEQ * DINNER;   // +delb: dbc partials pre-delta; Smat post-scan
  float* delb = ws; ws += LSEQ * DINNER;
  float* scr  = ws; ws += LSEQ * DINNER;   // scan summaries (was y2)
  u16* xn_bf   = (u16*)ws; ws += (LSEQ * DMODEL) / 2;
  u16* ycat_bf = (u16*)ws; ws += LSEQ * DINNER;
  u16* ypro_bf = (u16*)ws; ws += (LSEQ * DINNER) / 2;
  u16* Wb      = (u16*)ws;
  u16* in_w_bf = Wb;
  u16* pw_bf   = in_w_bf + 3072 * 768;
  u16* wA_bf   = pw_bf + 1536 * 3072;
  u16* wVT_bf  = wA_bf + 1024 * 1536;
  u16* ow_bf   = wVT_bf + 1536 * 1536;

  // aliases (verified live ranges)
  float* dbc_part = delf;        // [2][16][1024][80] = 2.62M <= delf+delb (3.1M contiguous)
  float* Smat    = delf;         // written after scans consume delf
  u16*   Smat_bf = (u16*)delb;
  u16*   vv_bf   = (u16*)xf;     // xf dead after scan
  u16*   vvT_bf  = (u16*)xb;     // xb dead after scan
  u16*   g_bf    = ypro_bf;      // ypro last read by vv gemm
  const int QS = 2 * NQ * DINNER * DSTATE;  // 196608
  float* qsP   = scr;            // scan summaries live only around scan phase
  float* qsQ   = scr + QS;
  float* qcar  = scr + 2 * QS;   // 3*QS = 589824 < LSEQ*DINNER

  hipMemcpyAsync(xbuf, in_x, sizeof(float) * LSEQ * DMODEL,
                 hipMemcpyDeviceToDevice, stream);

  dim3 blk(256);
  for (int layer = 0; layer < NLAYER; layer++) {
    const float* nw  = norm_w    + (size_t)layer * DMODEL;
    const float* iw  = in_proj_w + (size_t)layer * 2 * DINNER * DMODEL;
    const float* cfw = conv_f_w  + (size_t)layer * DINNER * KCONV;
    const float* cfb = conv_f_b  + (size_t)layer * DINNER;
    const float* cbw = conv_b_w  + (size_t)layer * DINNER * KCONV;
    const float* cbb = conv_b_b  + (size_t)layer * DINNER;
    const float* xfw = xproj_f_w + (size_t)layer * DBC * DINNER;
    const float* xbw = xproj_b_w + (size_t)layer * DBC * DINNER;
    const float* dfw = dt_f_w    + (size_t)layer * DINNER * DRANK;
    const float* dfb = dt_f_b    + (size_t)layer * DINNER;
    const float* dbw = dt_b_w    + (size_t)layer * DINNER * DRANK;
    const float* dbb = dt_b_b    + (size_t)layer * DINNER;
    const float* Af  = A_log_f   + (size_t)layer * DINNER * DSTATE;
    const float* Df  = D_f       + (size_t)layer * DINNER;
    const float* Ab  = A_log_b   + (size_t)layer * DINNER * DSTATE;
    const float* Db  = D_b       + (size_t)layer * DINNER;
    const float* ow  = out_w     + (size_t)layer * DMODEL * DINNER;
    const float* wA  = token_wA  + (size_t)layer * LSEQ * DINNER;
    const float* wV  = token_wV  + (size_t)layer * DINNER * DINNER;
    const float* pw  = pro_w     + (size_t)layer * DINNER * 2 * DINNER;
    const float* pb  = pro_b     + (size_t)layer * DINNER;

    // weight conversions for this layer
    cvt_k<<<(3072 * 768 / 4 + 255) / 256, blk, 0, stream>>>(iw, in_w_bf, 3072 * 768 / 4);
    cvt_k<<<(1536 * 3072 / 4 + 255) / 256, blk, 0, stream>>>(pw, pw_bf, 1536 * 3072 / 4);
    cvt_k<<<(1024 * 1536 / 4 + 255) / 256, blk, 0, stream>>>(wA, wA_bf, 1024 * 1536 / 4);
    cvt_k<<<(768 * 1536 / 4 + 255) / 256, blk, 0, stream>>>(ow, ow_bf, 768 * 1536 / 4);
    transcvt_k<<<dim3(1536 / 32, 1536 / 32), blk, 0, stream>>>(wV, wVT_bf, 1536, 1536);

    rmsnorm_k<<<LSEQ, blk, 0, stream>>>(xbuf, nw, xn_bf);

    // xz = xn @ in_w^T   [1024,3072] k=768
    mgemm_k<0><<<dim3(3072 / 64, LSEQ / 64), blk, 0, stream>>>(
        xn_bf, DMODEL, in_w_bf, DMODEL, xz, 2 * DINNER, DMODEL, nullptr, nullptr, 0);

    conv_silu_k<<<dim3((LSEQ * DINNER) / 256, 2), blk, 0, stream>>>(
        xz, cfw, cfb, cbw, cbb, xf, xb);

    // dbc = x @ xproj^T  [1024,80] k=1536
    thin_gemm_k<<<dim3(LSEQ / TG_R, TG_KS, 2), blk, 0, stream>>>(
        xf, xb, xfw, xbw, dbc_part);
    reduce_dbc_k<<<dim3((LSEQ * DBC) / 256, 2), blk, 0, stream>>>(
        dbc_part, dbcf, dbcb);

    // delta = softplus(dlt @ dt_w^T + dt_b)
    delta_gemm_k<<<dim3(DINNER / BN, LSEQ / BM, 2), blk, 0, stream>>>(
        dbcf, dbcb, dfw, dbw, dfb, dbb, delf, delb);

    // 3-phase scan: grid (96,4,2) = 768 blocks for A and C
    scan_a_k<<<dim3(DINNER / 16, NQ, 2), blk, 0, stream>>>(
        xf, xb, delf, delb, dbcf, dbcb, Af, Ab, qsP, qsQ);
    scan_b_k<<<(2 * DINNER * DSTATE) / 256, blk, 0, stream>>>(qsP, qsQ, qcar);
    scan_c_k<<<dim3(DINNER / 16, NQ, 2), blk, 0, stream>>>(
        xf, xb, delf, delb, dbcf, dbcb, Af, Ab, Df, Db, qcar, ycat_bf);

    // ypro = ycat @ pro_w^T + pro_b   [1024,1536] k=3072 -> bf16
    mgemm_k<9><<<dim3(DINNER / 64, LSEQ / 64), blk, 0, stream>>>(
        ycat_bf, 2 * DINNER, pw_bf, 2 * DINNER, ypro_bf, DINNER, 2 * DINNER,
        pb, nullptr, 0);

    // S = wA . ypro^T   [1024,1024] k=1536 -> fp32
    mgemm_k<0><<<dim3(LSEQ / 64, LSEQ / 64), blk, 0, stream>>>(
        wA_bf, DINNER, ypro_bf, DINNER, Smat, LSEQ, DINNER, nullptr, nullptr, 0);
    softmax_k<<<LSEQ, blk, 0, stream>>>(Smat, Smat_bf);

    // vv = ypro @ wV    [1024,1536] k=1536 -> bf16 (B = wV^T)
    mgemm_k<8><<<dim3(DINNER / 64, LSEQ / 64), blk, 0, stream>>>(
        ypro_bf, DINNER, wVT_bf, DINNER, vv_bf, DINNER, DINNER, nullptr, nullptr, 0);

    // vvT[e][l] = vv[l][e]
    transpose16_k<<<dim3(DINNER / 32, LSEQ / 32), blk, 0, stream>>>(
        vv_bf, vvT_bf, LSEQ, DINNER);

    // g = (att @ vv) * silu(z)  [1024,1536] k=1024 -> bf16 (fused epilogue)
    mgemm_k<24><<<dim3(DINNER / 64, LSEQ / 64), blk, 0, stream>>>(
        Smat_bf, LSEQ, vvT_bf, LSEQ, g_bf, DINNER, LSEQ,
        nullptr, xz + DINNER, 2 * DINNER);

    // x_next = x + g @ out_w^T   [1024,768] k=1536
    float* target = (layer == NLAYER - 1) ? (float*)d_out : xbuf;
    mgemm_k<4><<<dim3(DMODEL / 64, LSEQ / 64), blk, 0, stream>>>(
        g_bf, DINNER, ow_bf, DINNER, target, DMODEL, DINNER,
        nullptr, xbuf, DMODEL);
  }
}

// Round 11
// 423.495 us; speedup vs baseline: 2.9674x; 1.0853x over previous
//
#include <hip/hip_runtime.h>
#include <hip/hip_bf16.h>
#include <math.h>
#include <stdint.h>

#define LSEQ 1024
#define DMODEL 768
#define DINNER 1536
#define DSTATE 16
#define DRANK 48
#define KCONV 4
#define NLAYER 2
#define DBC 80  // DRANK + 2*DSTATE
#define NQ 4            // L quarters for the 3-phase scan
#define QL (LSEQ / NQ)  // 256
#define QCH (QL / 16)   // 16 steps per chunk

typedef unsigned short u16;
typedef __attribute__((ext_vector_type(8))) __bf16 bf16x8;
typedef __attribute__((ext_vector_type(4))) float f32x4;
typedef __attribute__((ext_vector_type(4))) unsigned short us4;

__device__ __forceinline__ u16 f2bf(float f) {
  union { float f; unsigned u; } v; v.f = f;
  unsigned r = v.u + 0x7fffu + ((v.u >> 16) & 1u);  // RNE
  return (u16)(r >> 16);
}
__device__ __forceinline__ float bf2f(u16 u) {
  union { unsigned u; float f; } v; v.u = ((unsigned)u) << 16;
  return v.f;
}

// CK-style addrspace casts for global_load_lds (direct HBM->LDS DMA, 16B/lane)
__device__ __forceinline__ void gload16(const void* g, void* l) {
  auto gp = reinterpret_cast<const __attribute__((address_space(1))) uint32_t*>(
      reinterpret_cast<uintptr_t>(g));
  auto lp = reinterpret_cast<__attribute__((address_space(3))) uint32_t*>(
      reinterpret_cast<uintptr_t>(l));
  __builtin_amdgcn_global_load_lds(gp, lp, 16, 0, 0);
}

// ---------------- fused fp32 -> bf16 convert of 4 weight mats ----------------
#define CV0 589824              // 3072*768/4
#define CV1 (CV0 + 1179648)     // +1536*3072/4
#define CV2 (CV1 + 393216)      // +1024*1536/4
#define CV3 (CV2 + 294912)      // +768*1536/4 = 2457600 total float4s
__global__ __launch_bounds__(256) void cvt4_k(
    const float* __restrict__ i0, u16* __restrict__ o0,
    const float* __restrict__ i1, u16* __restrict__ o1,
    const float* __restrict__ i2, u16* __restrict__ o2,
    const float* __restrict__ i3, u16* __restrict__ o3) {
  int i = blockIdx.x * 256 + threadIdx.x;
  const float* in; u16* out; int off;
  if (i < CV0)      { in = i0; out = o0; off = i; }
  else if (i < CV1) { in = i1; out = o1; off = i - CV0; }
  else if (i < CV2) { in = i2; out = o2; off = i - CV1; }
  else              { in = i3; out = o3; off = i - CV2; }
  float4 v = ((const float4*)in)[off];
  us4 o; o[0] = f2bf(v.x); o[1] = f2bf(v.y); o[2] = f2bf(v.z); o[3] = f2bf(v.w);
  ((us4*)out)[off] = o;
}

// ---------------- fp32 -> bf16 transpose-convert ----------------
__global__ __launch_bounds__(256) void transcvt_k(const float* __restrict__ in,
                                                  u16* __restrict__ out,
                                                  int R, int C) {
  __shared__ float t[32][33];
  int c0 = blockIdx.x * 32, r0 = blockIdx.y * 32;
  int tx = threadIdx.x & 31, ty = threadIdx.x >> 5;
  for (int i = ty; i < 32; i += 8) t[i][tx] = in[(size_t)(r0 + i) * C + c0 + tx];
  __syncthreads();
  for (int i = ty; i < 32; i += 8)
    out[(size_t)(c0 + i) * R + r0 + tx] = f2bf(t[tx][i]);
}

// ---------------- bf16 -> bf16 transpose ----------------
__global__ __launch_bounds__(256) void transpose16_k(const u16* __restrict__ in,
                                                     u16* __restrict__ out,
                                                     int R, int C) {
  __shared__ u16 t[32][34];
  int c0 = blockIdx.x * 32, r0 = blockIdx.y * 32;
  int tx = threadIdx.x & 31, ty = threadIdx.x >> 5;
  for (int i = ty; i < 32; i += 8) t[i][tx] = in[(size_t)(r0 + i) * C + c0 + tx];
  __syncthreads();
  for (int i = ty; i < 32; i += 8)
    out[(size_t)(c0 + i) * R + r0 + tx] = t[tx][i];
}

// ---------------- rmsnorm (bf16 out) ----------------
__global__ __launch_bounds__(256) void rmsnorm_k(const float* __restrict__ x,
                                                 const float* __restrict__ w,
                                                 u16* __restrict__ xn) {
  int row = blockIdx.x;
  int tid = threadIdx.x;
  const float* xr = x + (size_t)row * DMODEL;
  float ss = 0.f;
  for (int j = tid; j < DMODEL; j += 256) { float v = xr[j]; ss += v * v; }
  __shared__ float red[256];
  red[tid] = ss; __syncthreads();
  for (int s = 128; s > 0; s >>= 1) { if (tid < s) red[tid] += red[tid + s]; __syncthreads(); }
  float scale = rsqrtf(red[0] / (float)DMODEL + 1e-5f);
  u16* outr = xn + (size_t)row * DMODEL;
  for (int j = tid; j < DMODEL; j += 256) outr[j] = f2bf(xr[j] * scale * w[j]);
}

// ---------------- MFMA bf16 GEMM: 64x64 tile, BK=64, occupancy-first --------
// EPI bit0: +bias[n]; bit2: +resid fp32; bit3: bf16 output; bit4: *silu(resid).
template<int EPI>
__global__ __launch_bounds__(256) void mgemm_k(
    const u16* __restrict__ A, int lda,
    const u16* __restrict__ B, int ldb,
    void* __restrict__ Cv, int ldc, int K,
    const float* __restrict__ bias,
    const float* __restrict__ resid, int ldr)
{
  __shared__ u16 As[2][64 * 64];
  __shared__ u16 Bs[2][64 * 64];
  const int tid = threadIdx.x;
  const int lane = tid & 63;
  const int w = tid >> 6;

  const int nbx = gridDim.x;
  int bid = blockIdx.y * nbx + blockIdx.x;
  const int nwg = nbx * gridDim.y;
  bid = (bid & 7) * (nwg >> 3) + (bid >> 3);
  const int bm = (bid / nbx) * 64;
  const int bn = (bid % nbx) * 64;

  const int srow = lane >> 3;
  const int scs = (lane & 7) ^ srow;
  const int gA = 2 * w;
  const u16* Asrc0 = A + (size_t)(bm + gA * 8 + srow) * lda + scs * 8;
  const u16* Asrc1 = Asrc0 + (size_t)8 * lda;
  const u16* Bsrc0 = B + (size_t)(bn + gA * 8 + srow) * ldb + scs * 8;
  const u16* Bsrc1 = Bsrc0 + (size_t)8 * ldb;
  const int d0 = gA * 512;
  const int d1 = d0 + 512;

  const int fr = lane & 15;
  const int fs = lane >> 4;
  const int wm = (w >> 1) * 32;
  const int wn = (w & 1) * 32;
  int aoff[2][2], boff[2][2];
#pragma unroll
  for (int i = 0; i < 2; i++)
#pragma unroll
    for (int h = 0; h < 2; h++) {
      const int g = h * 4 + fs;
      aoff[i][h] = (wm + i * 16 + fr) * 64 + (g ^ (fr & 7)) * 8;
      boff[i][h] = (wn + i * 16 + fr) * 64 + (g ^ (fr & 7)) * 8;
    }

  f32x4 acc[2][2];
#pragma unroll
  for (int i = 0; i < 2; i++)
#pragma unroll
    for (int j = 0; j < 2; j++) acc[i][j] = (f32x4){0.f, 0.f, 0.f, 0.f};

#define STAGE(buf, k0) do { \
    gload16(Asrc0 + (k0), &As[buf][d0]); \
    gload16(Asrc1 + (k0), &As[buf][d1]); \
    gload16(Bsrc0 + (k0), &Bs[buf][d0]); \
    gload16(Bsrc1 + (k0), &Bs[buf][d1]); \
  } while (0)

  const int nk = K >> 6;
  STAGE(0, 0);

  for (int t = 0; t < nk; t++) {
    const int buf = t & 1;
    __syncthreads();
    if (t + 1 < nk) STAGE(buf ^ 1, (t + 1) << 6);
    const u16* As_ = As[buf];
    const u16* Bs_ = Bs[buf];
#pragma unroll
    for (int h = 0; h < 2; h++) {
      bf16x8 a0 = *reinterpret_cast<const bf16x8*>(As_ + aoff[0][h]);
      bf16x8 a1 = *reinterpret_cast<const bf16x8*>(As_ + aoff[1][h]);
      bf16x8 b0 = *reinterpret_cast<const bf16x8*>(Bs_ + boff[0][h]);
      bf16x8 b1 = *reinterpret_cast<const bf16x8*>(Bs_ + boff[1][h]);
      acc[0][0] = __builtin_amdgcn_mfma_f32_16x16x32_bf16(a0, b0, acc[0][0], 0, 0, 0);
      acc[0][1] = __builtin_amdgcn_mfma_f32_16x16x32_bf16(a0, b1, acc[0][1], 0, 0, 0);
      acc[1][0] = __builtin_amdgcn_mfma_f32_16x16x32_bf16(a1, b0, acc[1][0], 0, 0, 0);
      acc[1][1] = __builtin_amdgcn_mfma_f32_16x16x32_bf16(a1, b1, acc[1][1], 0, 0, 0);
    }
  }
#undef STAGE

#pragma unroll
  for (int i = 0; i < 2; i++) {
#pragma unroll
    for (int j = 0; j < 2; j++) {
      const int col = bn + wn + j * 16 + fr;
      const int row0 = bm + wm + i * 16 + fs * 4;
      float bv = (EPI & 1) ? bias[col] : 0.f;
#pragma unroll
      for (int r = 0; r < 4; r++) {
        float v = acc[i][j][r] + bv;
        if (EPI & 4) v += resid[(size_t)(row0 + r) * ldr + col];
        if (EPI & 16) {
          float z = resid[(size_t)(row0 + r) * ldr + col];
          v *= z / (1.f + __expf(-z));
        }
        if (EPI & 8) ((u16*)Cv)[(size_t)(row0 + r) * ldc + col] = f2bf(v);
        else         ((float*)Cv)[(size_t)(row0 + r) * ldc + col] = v;
      }
    }
  }
}

// ---------------- fused S + vv GEMM (both consume ypro, K=1536) --------------
// blocks [0,256): S = wA . ypro^T -> fp32 Smat [1024][1024]
// blocks [256,640): vv = ypro . wVT^T -> bf16 vv_bf [1024][1536]
__global__ __launch_bounds__(256) void svgemm_k(
    const u16* __restrict__ wA, const u16* __restrict__ ypro,
    const u16* __restrict__ wVT,
    float* __restrict__ Smat, u16* __restrict__ vv)
{
  __shared__ u16 As[2][64 * 64];
  __shared__ u16 Bs[2][64 * 64];
  const int tid = threadIdx.x;
  const int lane = tid & 63;
  const int w = tid >> 6;

  int bid = blockIdx.x;                    // 640 blocks
  bid = (bid & 7) * 80 + (bid >> 3);       // bijective XCD swizzle (640/8=80)
  const bool is_s = bid < 256;
  const u16* A;
  const u16* B;
  int bm, bn;
  if (is_s) { A = wA;   B = ypro; bm = (bid >> 4) * 64;         bn = (bid & 15) * 64; }
  else      { A = ypro; B = wVT;  bm = ((bid - 256) / 24) * 64; bn = ((bid - 256) % 24) * 64; }

  const int srow = lane >> 3;
  const int scs = (lane & 7) ^ srow;
  const int gA = 2 * w;
  const u16* Asrc0 = A + (size_t)(bm + gA * 8 + srow) * DINNER + scs * 8;
  const u16* Asrc1 = Asrc0 + (size_t)8 * DINNER;
  const u16* Bsrc0 = B + (size_t)(bn + gA * 8 + srow) * DINNER + scs * 8;
  const u16* Bsrc1 = Bsrc0 + (size_t)8 * DINNER;
  const int d0 = gA * 512;
  const int d1 = d0 + 512;

  const int fr = lane & 15;
  const int fs = lane >> 4;
  const int wm = (w >> 1) * 32;
  const int wn = (w & 1) * 32;
  int aoff[2][2], boff[2][2];
#pragma unroll
  for (int i = 0; i < 2; i++)
#pragma unroll
    for (int h = 0; h < 2; h++) {
      const int g = h * 4 + fs;
      aoff[i][h] = (wm + i * 16 + fr) * 64 + (g ^ (fr & 7)) * 8;
      boff[i][h] = (wn + i * 16 + fr) * 64 + (g ^ (fr & 7)) * 8;
    }

  f32x4 acc[2][2];
#pragma unroll
  for (int i = 0; i < 2; i++)
#pragma unroll
    for (int j = 0; j < 2; j++) acc[i][j] = (f32x4){0.f, 0.f, 0.f, 0.f};

#define STAGE(buf, k0) do { \
    gload16(Asrc0 + (k0), &As[buf][d0]); \
    gload16(Asrc1 + (k0), &As[buf][d1]); \
    gload16(Bsrc0 + (k0), &Bs[buf][d0]); \
    gload16(Bsrc1 + (k0), &Bs[buf][d1]); \
  } while (0)

  STAGE(0, 0);
  for (int t = 0; t < DINNER / 64; t++) {
    const int buf = t & 1;
    __syncthreads();
    if (t + 1 < DINNER / 64) STAGE(buf ^ 1, (t + 1) << 6);
    const u16* As_ = As[buf];
    const u16* Bs_ = Bs[buf];
#pragma unroll
    for (int h = 0; h < 2; h++) {
      bf16x8 a0 = *reinterpret_cast<const bf16x8*>(As_ + aoff[0][h]);
      bf16x8 a1 = *reinterpret_cast<const bf16x8*>(As_ + aoff[1][h]);
      bf16x8 b0 = *reinterpret_cast<const bf16x8*>(Bs_ + boff[0][h]);
      bf16x8 b1 = *reinterpret_cast<const bf16x8*>(Bs_ + boff[1][h]);
      acc[0][0] = __builtin_amdgcn_mfma_f32_16x16x32_bf16(a0, b0, acc[0][0], 0, 0, 0);
      acc[0][1] = __builtin_amdgcn_mfma_f32_16x16x32_bf16(a0, b1, acc[0][1], 0, 0, 0);
      acc[1][0] = __builtin_amdgcn_mfma_f32_16x16x32_bf16(a1, b0, acc[1][0], 0, 0, 0);
      acc[1][1] = __builtin_amdgcn_mfma_f32_16x16x32_bf16(a1, b1, acc[1][1], 0, 0, 0);
    }
  }
#undef STAGE

#pragma unroll
  for (int i = 0; i < 2; i++) {
#pragma unroll
    for (int j = 0; j < 2; j++) {
      const int col = bn + wn + j * 16 + fr;
      const int row0 = bm + wm + i * 16 + fs * 4;
#pragma unroll
      for (int r = 0; r < 4; r++) {
        float v = acc[i][j][r];
        if (is_s) Smat[(size_t)(row0 + r) * LSEQ + col] = v;
        else      vv[(size_t)(row0 + r) * DINNER + col] = f2bf(v);
      }
    }
  }
}

// ---------------- thin dbc GEMM (f+b merged): partial[dir][ks][1024][80] -----
#define TG_R 16
#define TG_KC 96
#define TG_KS 16

__global__ __launch_bounds__(256) void thin_gemm_k(
    const float* __restrict__ Af_, const float* __restrict__ Ab_,
    const float* __restrict__ Bf_, const float* __restrict__ Bb_,
    float* __restrict__ partial)
{
  __shared__ float As[TG_R][100];
  __shared__ float Bs[80][100];
  const float* A = blockIdx.z ? Ab_ : Af_;
  const float* B = blockIdx.z ? Bb_ : Bf_;
  float* part = partial + (size_t)blockIdx.z * TG_KS * LSEQ * DBC;
  const int tid = threadIdx.x;
  const int m0 = blockIdx.x * TG_R;
  const int ks = blockIdx.y;
  const int k0 = ks * TG_KC;

  for (int i = tid; i < 384; i += 256) {
    int r = i / 24, q = i % 24;
    *(float4*)&As[r][q * 4] = *(const float4*)(A + (size_t)(m0 + r) * DINNER + k0 + q * 4);
  }
  for (int i = tid; i < 1920; i += 256) {
    int r = i / 24, q = i % 24;
    *(float4*)&Bs[r][q * 4] = *(const float4*)(B + (size_t)r * DINNER + k0 + q * 4);
  }
  __syncthreads();

  const int r = tid >> 4;
  const int c0 = (tid & 15) * 5;
  float acc[5] = {};
  for (int k = 0; k < TG_KC; k++) {
    float a = As[r][k];
#pragma unroll
    for (int j = 0; j < 5; j++) acc[j] += a * Bs[c0 + j][k];
  }
  float* out = part + ((size_t)ks * LSEQ + m0 + r) * DBC + c0;
#pragma unroll
  for (int j = 0; j < 5; j++) out[j] = acc[j];
}

__global__ __launch_bounds__(256) void reduce_dbc_k(const float* __restrict__ partial,
                                                    float* __restrict__ outf,
                                                    float* __restrict__ outb) {
  int i = blockIdx.x * 256 + threadIdx.x;
  const float* part = partial + (size_t)blockIdx.y * TG_KS * LSEQ * DBC;
  float s = 0.f;
#pragma unroll
  for (int ks = 0; ks < TG_KS; ks++) s += part[(size_t)ks * (LSEQ * DBC) + i];
  (blockIdx.y ? outb : outf)[i] = s;
}

// ---------------- delta = softplus(dlt @ dt_w^T + dt_b), f+b merged, bf16 out
#define BM 64
#define BN 64
#define BK 16

__global__ __launch_bounds__(256) void delta_gemm_k(
    const float* __restrict__ A0, const float* __restrict__ A1,
    const float* __restrict__ B0, const float* __restrict__ B1,
    const float* __restrict__ b0, const float* __restrict__ b1,
    u16* __restrict__ C0, u16* __restrict__ C1)
{
  __shared__ float Asf[BK][BM];
  __shared__ float Bsf[BK][BN + 4];
  const float* A = blockIdx.z ? A1 : A0;
  const float* B = blockIdx.z ? B1 : B0;
  const float* bias = blockIdx.z ? b1 : b0;
  u16* C = blockIdx.z ? C1 : C0;
  const int tid = threadIdx.x;
  const int bm = blockIdx.y * BM;
  const int bn = blockIdx.x * BN;
  const int ar = tid >> 2;
  const int ak = (tid & 3) << 2;
  const int ty = tid >> 4, tx = tid & 15;
  float acc[4][4] = {};

  for (int k0 = 0; k0 < DRANK; k0 += BK) {
    float4 av = *(const float4*)(A + (size_t)(bm + ar) * DBC + k0 + ak);
    float4 bv = *(const float4*)(B + (size_t)(bn + ar) * DRANK + k0 + ak);
    __syncthreads();
    Asf[ak + 0][ar] = av.x; Asf[ak + 1][ar] = av.y;
    Asf[ak + 2][ar] = av.z; Asf[ak + 3][ar] = av.w;
    Bsf[ak + 0][ar] = bv.x; Bsf[ak + 1][ar] = bv.y;
    Bsf[ak + 2][ar] = bv.z; Bsf[ak + 3][ar] = bv.w;
    __syncthreads();
#pragma unroll
    for (int kk = 0; kk < BK; kk++) {
      float4 a4 = *(const float4*)&Asf[kk][ty * 4];
      float4 b4 = *(const float4*)&Bsf[kk][tx * 4];
      float a[4] = {a4.x, a4.y, a4.z, a4.w};
      float b[4] = {b4.x, b4.y, b4.z, b4.w};
#pragma unroll
      for (int i = 0; i < 4; i++)
#pragma unroll
        for (int j = 0; j < 4; j++)
          acc[i][j] += a[i] * b[j];
    }
  }

#pragma unroll
  for (int i = 0; i < 4; i++) {
    int row = bm + ty * 4 + i;
#pragma unroll
    for (int j = 0; j < 4; j++) {
      int col = bn + tx * 4 + j;
      float v = acc[i][j] + bias[col];
      v = (v > 20.f) ? v : log1pf(__expf(v));
      C[(size_t)row * DINNER + col] = f2bf(v);
    }
  }
}

// ---------------- causal depthwise conv + silu (both directions) -------------
__global__ __launch_bounds__(256) void conv_silu_k(
    const float* __restrict__ xz,
    const float* __restrict__ wf, const float* __restrict__ bf,
    const float* __restrict__ wb, const float* __restrict__ bb,
    float* __restrict__ xf, float* __restrict__ xb)
{
  int idx = blockIdx.x * 256 + threadIdx.x;
  int dir = blockIdx.y;
  if (idx >= LSEQ * DINNER) return;
  int l = idx / DINNER, c = idx % DINNER;
  const float* w = (dir ? wb : wf) + c * KCONV;
  float acc = (dir ? bb : bf)[c];
#pragma unroll
  for (int k = 0; k < KCONV; k++) {
    int ls = l - (KCONV - 1) + k;
    if (ls >= 0) {
      int lsrc = dir ? (LSEQ - 1 - ls) : ls;
      acc += w[k] * xz[(size_t)lsrc * (2 * DINNER) + c];
    }
  }
  float sv = acc / (1.f + __expf(-acc));
  (dir ? xb : xf)[idx] = sv;
}

// ---------------- 3-phase L-split scan (bf16 delta) ---------------------------
__global__ __launch_bounds__(256) void scan_a_k(
    const float* __restrict__ xcf, const float* __restrict__ xcb,
    const u16* __restrict__ dltf, const u16* __restrict__ dltb,
    const float* __restrict__ dbcf, const float* __restrict__ dbcb,
    const float* __restrict__ Af, const float* __restrict__ Ab,
    float* __restrict__ qsP, float* __restrict__ qsQ)  // [2][NQ][DINNER][16]
{
  __shared__ float sP[16 * 16 * 16];
  __shared__ float sQ[16 * 16 * 16];
  const int dir = blockIdx.z;
  const int qid = blockIdx.y;
  const float* xc    = dir ? xcb : xcf;
  const u16*   delta = dir ? dltb : dltf;
  const float* dbc   = dir ? dbcb : dbcf;
  const float* A_log = dir ? Ab : Af;

  const int tid = threadIdx.x;
  const int c = tid >> 4;
  const int dl = tid & 15;
  const int d = blockIdx.x * 16 + dl;

  float Aa[DSTATE];
#pragma unroll
  for (int s = 0; s < DSTATE; s++) Aa[s] = -__expf(A_log[(size_t)d * DSTATE + s]);

  float aP[DSTATE], q[DSTATE];
#pragma unroll
  for (int s = 0; s < DSTATE; s++) { aP[s] = 1.f; q[s] = 0.f; }
  const int l0 = qid * QL + c * QCH;
  for (int i = 0; i < QCH; i++) {
    int l = l0 + i;
    float dt = bf2f(delta[(size_t)l * DINNER + d]);
    float dx = dt * xc[(size_t)l * DINNER + d];
    const float* bm = dbc + (size_t)l * DBC + DRANK;
#pragma unroll
    for (int s = 0; s < DSTATE; s++) {
      float a = __expf(dt * Aa[s]);
      q[s] = a * q[s] + dx * bm[s];
      aP[s] *= a;
    }
  }
#pragma unroll
  for (int s = 0; s < DSTATE; s++) {
    sP[(c * 16 + dl) * 16 + s] = aP[s];
    sQ[(c * 16 + dl) * 16 + s] = q[s];
  }
  __syncthreads();

  {  // phase 2: serial over 16 chunks; thread = (d2, s2)
    const int d2 = tid >> 4, s2 = tid & 15;
    float h = 0.f, P = 1.f;
    for (int cc = 0; cc < 16; cc++) {
      int idx = (cc * 16 + d2) * 16 + s2;
      float a = sP[idx];
      h = a * h + sQ[idx];
      P *= a;
    }
    size_t o = (((size_t)dir * NQ + qid) * DINNER + blockIdx.x * 16 + d2) * 16 + s2;
    qsP[o] = P;
    qsQ[o] = h;
  }
}

__global__ __launch_bounds__(256) void scan_c_k(
    const float* __restrict__ xcf, const float* __restrict__ xcb,
    const u16* __restrict__ dltf, const u16* __restrict__ dltb,
    const float* __restrict__ dbcf, const float* __restrict__ dbcb,
    const float* __restrict__ Af, const float* __restrict__ Ab,
    const float* __restrict__ Df, const float* __restrict__ Db,
    const float* __restrict__ qsP, const float* __restrict__ qsQ,
    u16* __restrict__ ycat)
{
  __shared__ float sP[16 * 16 * 16];
  __shared__ float sQ[16 * 16 * 16];
  const int dir = blockIdx.z;
  const int qid = blockIdx.y;
  const float* xc    = dir ? xcb : xcf;
  const u16*   delta = dir ? dltb : dltf;
  const float* dbc   = dir ? dbcb : dbcf;
  const float* A_log = dir ? Ab : Af;
  const float* Dvec  = dir ? Db : Df;
  const int col_off  = dir ? DINNER : 0;

  const int tid = threadIdx.x;
  const int c = tid >> 4;
  const int dl = tid & 15;
  const int d = blockIdx.x * 16 + dl;

  float Aa[DSTATE];
#pragma unroll
  for (int s = 0; s < DSTATE; s++) Aa[s] = -__expf(A_log[(size_t)d * DSTATE + s]);

  float aP[DSTATE], q[DSTATE];
#pragma unroll
  for (int s = 0; s < DSTATE; s++) { aP[s] = 1.f; q[s] = 0.f; }
  const int l0 = qid * QL + c * QCH;
  for (int i = 0; i < QCH; i++) {
    int l = l0 + i;
    float dt = bf2f(delta[(size_t)l * DINNER + d]);
    float dx = dt * xc[(size_t)l * DINNER + d];
    const float* bm = dbc + (size_t)l * DBC + DRANK;
#pragma unroll
    for (int s = 0; s < DSTATE; s++) {
      float a = __expf(dt * Aa[s]);
      q[s] = a * q[s] + dx * bm[s];
      aP[s] *= a;
    }
  }
#pragma unroll
  for (int s = 0; s < DSTATE; s++) {
    sP[(c * 16 + dl) * 16 + s] = aP[s];
    sQ[(c * 16 + dl) * 16 + s] = q[s];
  }
  __syncthreads();

  {  // phase 2 with inline quarter carry (combine q < qid; <=3 steps)
    const int d2 = tid >> 4, s2 = tid & 15;
    size_t base = ((size_t)dir * NQ * DINNER + blockIdx.x * 16 + d2) * 16 + s2;
    float h = 0.f;
    for (int qq = 0; qq < qid; qq++) {
      size_t o = base + (size_t)qq * DINNER * 16;
      h = qsP[o] * h + qsQ[o];
    }
    for (int cc = 0; cc < 16; cc++) {
      int idx = (cc * 16 + d2) * 16 + s2;
      float a = sP[idx], qq = sQ[idx];
      sP[idx] = h;
      h = a * h + qq;
    }
  }
  __syncthreads();

  float hs[DSTATE];
#pragma unroll
  for (int s = 0; s < DSTATE; s++) hs[s] = sP[(c * 16 + dl) * 16 + s];
  const float Dd = Dvec[d];
  for (int i = 0; i < QCH; i++) {
    int l = l0 + i;
    float dt = bf2f(delta[(size_t)l * DINNER + d]);
    float xv = xc[(size_t)l * DINNER + d];
    float dx = dt * xv;
    const float* bm = dbc + (size_t)l * DBC + DRANK;
    const float* cm = bm + DSTATE;
    float y = 0.f;
#pragma unroll
    for (int s = 0; s < DSTATE; s++) {
      float a = __expf(dt * Aa[s]);
      hs[s] = a * hs[s] + dx * bm[s];
      y += hs[s] * cm[s];
    }
    ycat[(size_t)l * (2 * DINNER) + col_off + d] = f2bf(y + Dd * xv);
  }
}

// ---------------- row softmax (fp32 in, bf16 out) ----------------
__global__ __launch_bounds__(256) void softmax_k(const float* __restrict__ S,
                                                 u16* __restrict__ P) {
  int row = blockIdx.x, tid = threadIdx.x;
  __shared__ float buf[LSEQ];
  __shared__ float red[256];
  const float* r = S + (size_t)row * LSEQ;
  float m = -1e30f;
  for (int j = tid; j < LSEQ; j += 256) { float v = r[j]; buf[j] = v; m = fmaxf(m, v); }
  red[tid] = m; __syncthreads();
  for (int s = 128; s > 0; s >>= 1) { if (tid < s) red[tid] = fmaxf(red[tid], red[tid + s]); __syncthreads(); }
  m = red[0];
  __syncthreads();
  float sum = 0.f;
  for (int j = tid; j < LSEQ; j += 256) { float e = __expf(buf[j] - m); buf[j] = e; sum += e; }
  red[tid] = sum; __syncthreads();
  for (int s = 128; s > 0; s >>= 1) { if (tid < s) red[tid] += red[tid + s]; __syncthreads(); }
  float inv = 1.f / red[0];
  u16* pr = P + (size_t)row * LSEQ;
  for (int j = tid; j < LSEQ; j += 256) pr[j] = f2bf(buf[j] * inv);
}

extern "C" void kernel_launch(void* const* d_in, const int* in_sizes, int n_in,
                              void* d_out, int out_size, void* d_ws, size_t ws_size,
                              hipStream_t stream) {
  const float* in_x      = (const float*)d_in[0];
  const float* norm_w    = (const float*)d_in[1];
  const float* in_proj_w = (const float*)d_in[2];
  const float* conv_f_w  = (const float*)d_in[3];
  const float* conv_f_b  = (const float*)d_in[4];
  const float* conv_b_w  = (const float*)d_in[5];
  const float* conv_b_b  = (const float*)d_in[6];
  const float* xproj_f_w = (const float*)d_in[7];
  const float* xproj_b_w = (const float*)d_in[8];
  const float* dt_f_w    = (const float*)d_in[9];
  const float* dt_f_b    = (const float*)d_in[10];
  const float* dt_b_w    = (const float*)d_in[11];
  const float* dt_b_b    = (const float*)d_in[12];
  const float* A_log_f   = (const float*)d_in[13];
  const float* D_f       = (const float*)d_in[14];
  const float* A_log_b   = (const float*)d_in[15];
  const float* D_b       = (const float*)d_in[16];
  const float* out_w     = (const float*)d_in[17];
  const float* token_wA  = (const float*)d_in[18];
  const float* token_wV  = (const float*)d_in[19];
  const float* pro_w     = (const float*)d_in[20];
  const float* pro_b     = (const float*)d_in[21];

  // ---- workspace carve (fp32 units) ----
  float* ws = (float*)d_ws;
  float* xbuf = ws; ws += LSEQ * DMODEL;
  float* xz   = ws; ws += LSEQ * 2 * DINNER;
  float* xf   = ws; ws += LSEQ * DINNER;
  float* xb   = ws; ws += LSEQ * DINNER;
  float* dbcf = ws; ws += LSEQ * DBC;
  float* dbcb = ws; ws += LSEQ * DBC;
  float* delf_r = ws; ws += LSEQ * DINNER;  // region: dbc partials; bf16 delta; Smat
  float* delb_r = ws; ws += LSEQ * DINNER;
  float* scr  = ws; ws += LSEQ * DINNER;    // scan quarter summaries
  u16* xn_bf   = (u16*)ws; ws += (LSEQ * DMODEL) / 2;
  u16* ycat_bf = (u16*)ws; ws += LSEQ * DINNER;
  u16* ypro_bf = (u16*)ws; ws += (LSEQ * DINNER) / 2;
  u16* Wb      = (u16*)ws;
  u16* in_w_bf = Wb;
  u16* pw_bf   = in_w_bf + 3072 * 768;
  u16* wA_bf   = pw_bf + 1536 * 3072;
  u16* wVT_bf  = wA_bf + 1024 * 1536;
  u16* ow_bf   = wVT_bf + 1536 * 1536;

  // aliases (verified live ranges)
  float* dbc_part = delf_r;       // [2][16][1024][80] = 2.62M <= delf_r+delb_r (3.1M contiguous)
  u16*   delf_bf  = (u16*)delf_r; // bf16 delta written after partials reduced
  u16*   delb_bf  = (u16*)delb_r;
  float* Smat     = delf_r;       // written (fused S+vv) after scans consume delta
  u16*   Smat_bf  = (u16*)delb_r;
  u16*   vv_bf    = (u16*)xf;     // xf dead after scan
  u16*   vvT_bf   = (u16*)xb;     // xb dead after scan
  u16*   g_bf     = ypro_bf;      // ypro last read by fused S+vv gemm
  const int QS = 2 * NQ * DINNER * DSTATE;  // 196608
  float* qsP   = scr;
  float* qsQ   = scr + QS;        // 2*QS = 393216 < LSEQ*DINNER

  dim3 blk(256);
  for (int layer = 0; layer < NLAYER; layer++) {
    const float* nw  = norm_w    + (size_t)layer * DMODEL;
    const float* iw  = in_proj_w + (size_t)layer * 2 * DINNER * DMODEL;
    const float* cfw = conv_f_w  + (size_t)layer * DINNER * KCONV;
    const float* cfb = conv_f_b  + (size_t)layer * DINNER;
    const float* cbw = conv_b_w  + (size_t)layer * DINNER * KCONV;
    const float* cbb = conv_b_b  + (size_t)layer * DINNER;
    const float* xfw = xproj_f_w + (size_t)layer * DBC * DINNER;
    const float* xbw = xproj_b_w + (size_t)layer * DBC * DINNER;
    const float* dfw = dt_f_w    + (size_t)layer * DINNER * DRANK;
    const float* dfb = dt_f_b    + (size_t)layer * DINNER;
    const float* dbw = dt_b_w    + (size_t)layer * DINNER * DRANK;
    const float* dbb = dt_b_b    + (size_t)layer * DINNER;
    const float* Af  = A_log_f   + (size_t)layer * DINNER * DSTATE;
    const float* Df  = D_f       + (size_t)layer * DINNER;
    const float* Ab  = A_log_b   + (size_t)layer * DINNER * DSTATE;
    const float* Db  = D_b       + (size_t)layer * DINNER;
    const float* ow  = out_w     + (size_t)layer * DMODEL * DINNER;
    const float* wA  = token_wA  + (size_t)layer * LSEQ * DINNER;
    const float* wV  = token_wV  + (size_t)layer * DINNER * DINNER;
    const float* pw  = pro_w     + (size_t)layer * DINNER * 2 * DINNER;
    const float* pb  = pro_b     + (size_t)layer * DINNER;

    const float* xsrc = (layer == 0) ? in_x : xbuf;   // residual stream source

    // weight conversions for this layer (one fused dispatch + wV transpose)
    cvt4_k<<<CV3 / 256, blk, 0, stream>>>(iw, in_w_bf, pw, pw_bf, wA, wA_bf, ow, ow_bf);
    transcvt_k<<<dim3(1536 / 32, 1536 / 32), blk, 0, stream>>>(wV, wVT_bf, 1536, 1536);

    rmsnorm_k<<<LSEQ, blk, 0, stream>>>(xsrc, nw, xn_bf);

    // xz = xn @ in_w^T   [1024,3072] k=768
    mgemm_k<0><<<dim3(3072 / 64, LSEQ / 64), blk, 0, stream>>>(
        xn_bf, DMODEL, in_w_bf, DMODEL, xz, 2 * DINNER, DMODEL, nullptr, nullptr, 0);

    conv_silu_k<<<dim3((LSEQ * DINNER) / 256, 2), blk, 0, stream>>>(
        xz, cfw, cfb, cbw, cbb, xf, xb);

    // dbc = x @ xproj^T  [1024,80] k=1536
    thin_gemm_k<<<dim3(LSEQ / TG_R, TG_KS, 2), blk, 0, stream>>>(
        xf, xb, xfw, xbw, dbc_part);
    reduce_dbc_k<<<dim3((LSEQ * DBC) / 256, 2), blk, 0, stream>>>(
        dbc_part, dbcf, dbcb);

    // delta = softplus(dlt @ dt_w^T + dt_b) -> bf16
    delta_gemm_k<<<dim3(DINNER / BN, LSEQ / BM, 2), blk, 0, stream>>>(
        dbcf, dbcb, dfw, dbw, dfb, dbb, delf_bf, delb_bf);

    // 3-phase scan: grid (96,4,2); carry combined inline in scan_c
    scan_a_k<<<dim3(DINNER / 16, NQ, 2), blk, 0, stream>>>(
        xf, xb, delf_bf, delb_bf, dbcf, dbcb, Af, Ab, qsP, qsQ);
    scan_c_k<<<dim3(DINNER / 16, NQ, 2), blk, 0, stream>>>(
        xf, xb, delf_bf, delb_bf, dbcf, dbcb, Af, Ab, Df, Db, qsP, qsQ, ycat_bf);

    // ypro = ycat @ pro_w^T + pro_b   [1024,1536] k=3072 -> bf16
    mgemm_k<9><<<dim3(DINNER / 64, LSEQ / 64), blk, 0, stream>>>(
        ycat_bf, 2 * DINNER, pw_bf, 2 * DINNER, ypro_bf, DINNER, 2 * DINNER,
        pb, nullptr, 0);

    // fused: S = wA.ypro^T (fp32) and vv = ypro.wV (bf16), one 640-block dispatch
    svgemm_k<<<640, blk, 0, stream>>>(wA_bf, ypro_bf, wVT_bf, Smat, vv_bf);
    softmax_k<<<LSEQ, blk, 0, stream>>>(Smat, Smat_bf);

    // vvT[e][l] = vv[l][e]
    transpose16_k<<<dim3(DINNER / 32, LSEQ / 32), blk, 0, stream>>>(
        vv_bf, vvT_bf, LSEQ, DINNER);

    // g = (att @ vv) * silu(z)  [1024,1536] k=1024 -> bf16 (fused epilogue)
    mgemm_k<24><<<dim3(DINNER / 64, LSEQ / 64), blk, 0, stream>>>(
        Smat_bf, LSEQ, vvT_bf, LSEQ, g_bf, DINNER, LSEQ,
        nullptr, xz + DINNER, 2 * DINNER);

    // x_next = x + g @ out_w^T   [1024,768] k=1536
    float* target = (layer == NLAYER - 1) ? (float*)d_out : xbuf;
    mgemm_k<4><<<dim3(DMODEL / 64, LSEQ / 64), blk, 0, stream>>>(
        g_bf, DINNER, ow_bf, DINNER, target, DMODEL, DINNER,
        nullptr, xsrc, DMODEL);
  }
}

// Round 13
// 413.816 us; speedup vs baseline: 3.0368x; 1.0234x over previous
//
#include <hip/hip_runtime.h>
#include <hip/hip_bf16.h>
#include <math.h>
#include <stdint.h>

#define LSEQ 1024
#define DMODEL 768
#define DINNER 1536
#define DSTATE 16
#define DRANK 48
#define KCONV 4
#define NLAYER 2
#define DBC 80  // DRANK + 2*DSTATE
#define NQ 8            // L-split for the 3-phase scan
#define QL (LSEQ / NQ)  // 128
#define SCH 8           // chunks per scan block
#define SCW 32          // channels per scan block (32*2B = full 64B line)
#define QCH (QL / SCH)  // 16 steps per chunk

typedef unsigned short u16;
typedef __attribute__((ext_vector_type(8))) __bf16 bf16x8;
typedef __attribute__((ext_vector_type(4))) float f32x4;
typedef __attribute__((ext_vector_type(4))) unsigned short us4;  // 4 u16 = 8 B

__device__ __forceinline__ u16 f2bf(float f) {
  union { float f; unsigned u; } v; v.f = f;
  unsigned r = v.u + 0x7fffu + ((v.u >> 16) & 1u);  // RNE
  return (u16)(r >> 16);
}
__device__ __forceinline__ float bf2f(u16 u) {
  union { unsigned u; float f; } v; v.u = ((unsigned)u) << 16;
  return v.f;
}

// CK-style addrspace casts for global_load_lds (direct HBM->LDS DMA, 16B/lane)
__device__ __forceinline__ void gload16(const void* g, void* l) {
  auto gp = reinterpret_cast<const __attribute__((address_space(1))) uint32_t*>(
      reinterpret_cast<uintptr_t>(g));
  auto lp = reinterpret_cast<__attribute__((address_space(3))) uint32_t*>(
      reinterpret_cast<uintptr_t>(l));
  __builtin_amdgcn_global_load_lds(gp, lp, 16, 0, 0);
}

// ---------------- fused fp32 -> bf16 convert of 4 weight mats ----------------
#define CV0 589824              // 3072*768/4
#define CV1 (CV0 + 1179648)     // +1536*3072/4
#define CV2 (CV1 + 393216)      // +1024*1536/4
#define CV3 (CV2 + 294912)      // +768*1536/4 = 2457600 total float4s
__global__ __launch_bounds__(256) void cvt4_k(
    const float* __restrict__ i0, u16* __restrict__ o0,
    const float* __restrict__ i1, u16* __restrict__ o1,
    const float* __restrict__ i2, u16* __restrict__ o2,
    const float* __restrict__ i3, u16* __restrict__ o3) {
  int i = blockIdx.x * 256 + threadIdx.x;
  const float* in; u16* out; int off;
  if (i < CV0)      { in = i0; out = o0; off = i; }
  else if (i < CV1) { in = i1; out = o1; off = i - CV0; }
  else if (i < CV2) { in = i2; out = o2; off = i - CV1; }
  else              { in = i3; out = o3; off = i - CV2; }
  float4 v = ((const float4*)in)[off];
  us4 o; o[0] = f2bf(v.x); o[1] = f2bf(v.y); o[2] = f2bf(v.z); o[3] = f2bf(v.w);
  ((us4*)out)[off] = o;
}

// ---------------- fp32 -> bf16 transpose-convert ----------------
__global__ __launch_bounds__(256) void transcvt_k(const float* __restrict__ in,
                                                  u16* __restrict__ out,
                                                  int R, int C) {
  __shared__ float t[32][33];
  int c0 = blockIdx.x * 32, r0 = blockIdx.y * 32;
  int tx = threadIdx.x & 31, ty = threadIdx.x >> 5;
  for (int i = ty; i < 32; i += 8) t[i][tx] = in[(size_t)(r0 + i) * C + c0 + tx];
  __syncthreads();
  for (int i = ty; i < 32; i += 8)
    out[(size_t)(c0 + i) * R + r0 + tx] = f2bf(t[tx][i]);
}

// ---------------- bf16 -> bf16 transpose ----------------
__global__ __launch_bounds__(256) void transpose16_k(const u16* __restrict__ in,
                                                     u16* __restrict__ out,
                                                     int R, int C) {
  __shared__ u16 t[32][34];
  int c0 = blockIdx.x * 32, r0 = blockIdx.y * 32;
  int tx = threadIdx.x & 31, ty = threadIdx.x >> 5;
  for (int i = ty; i < 32; i += 8) t[i][tx] = in[(size_t)(r0 + i) * C + c0 + tx];
  __syncthreads();
  for (int i = ty; i < 32; i += 8)
    out[(size_t)(c0 + i) * R + r0 + tx] = t[tx][i];
}

// ---------------- rmsnorm (bf16 out) ----------------
__global__ __launch_bounds__(256) void rmsnorm_k(const float* __restrict__ x,
                                                 const float* __restrict__ w,
                                                 u16* __restrict__ xn) {
  int row = blockIdx.x;
  int tid = threadIdx.x;
  const float* xr = x + (size_t)row * DMODEL;
  float ss = 0.f;
  for (int j = tid; j < DMODEL; j += 256) { float v = xr[j]; ss += v * v; }
  __shared__ float red[256];
  red[tid] = ss; __syncthreads();
  for (int s = 128; s > 0; s >>= 1) { if (tid < s) red[tid] += red[tid + s]; __syncthreads(); }
  float scale = rsqrtf(red[0] / (float)DMODEL + 1e-5f);
  u16* outr = xn + (size_t)row * DMODEL;
  for (int j = tid; j < DMODEL; j += 256) outr[j] = f2bf(xr[j] * scale * w[j]);
}

// ---------------- MFMA bf16 GEMM: 64x64 tile, BK=64, occupancy-first --------
// EPI bit0: +bias; bit2: +resid fp32; bit3: bf16 out; bit4: *silu(resid);
// bit5: resid is bf16.
template<int EPI>
__global__ __launch_bounds__(256) void mgemm_k(
    const u16* __restrict__ A, int lda,
    const u16* __restrict__ B, int ldb,
    void* __restrict__ Cv, int ldc, int K,
    const float* __restrict__ bias,
    const float* __restrict__ resid, int ldr)
{
  __shared__ u16 As[2][64 * 64];
  __shared__ u16 Bs[2][64 * 64];
  const int tid = threadIdx.x;
  const int lane = tid & 63;
  const int w = tid >> 6;

  const int nbx = gridDim.x;
  int bid = blockIdx.y * nbx + blockIdx.x;
  const int nwg = nbx * gridDim.y;
  bid = (bid & 7) * (nwg >> 3) + (bid >> 3);
  const int bm = (bid / nbx) * 64;
  const int bn = (bid % nbx) * 64;

  const int srow = lane >> 3;
  const int scs = (lane & 7) ^ srow;
  const int gA = 2 * w;
  const u16* Asrc0 = A + (size_t)(bm + gA * 8 + srow) * lda + scs * 8;
  const u16* Asrc1 = Asrc0 + (size_t)8 * lda;
  const u16* Bsrc0 = B + (size_t)(bn + gA * 8 + srow) * ldb + scs * 8;
  const u16* Bsrc1 = Bsrc0 + (size_t)8 * ldb;
  const int d0 = gA * 512;
  const int d1 = d0 + 512;

  const int fr = lane & 15;
  const int fs = lane >> 4;
  const int wm = (w >> 1) * 32;
  const int wn = (w & 1) * 32;
  int aoff[2][2], boff[2][2];
#pragma unroll
  for (int i = 0; i < 2; i++)
#pragma unroll
    for (int h = 0; h < 2; h++) {
      const int g = h * 4 + fs;
      aoff[i][h] = (wm + i * 16 + fr) * 64 + (g ^ (fr & 7)) * 8;
      boff[i][h] = (wn + i * 16 + fr) * 64 + (g ^ (fr & 7)) * 8;
    }

  f32x4 acc[2][2];
#pragma unroll
  for (int i = 0; i < 2; i++)
#pragma unroll
    for (int j = 0; j < 2; j++) acc[i][j] = (f32x4){0.f, 0.f, 0.f, 0.f};

#define STAGE(buf, k0) do { \
    gload16(Asrc0 + (k0), &As[buf][d0]); \
    gload16(Asrc1 + (k0), &As[buf][d1]); \
    gload16(Bsrc0 + (k0), &Bs[buf][d0]); \
    gload16(Bsrc1 + (k0), &Bs[buf][d1]); \
  } while (0)

  const int nk = K >> 6;
  STAGE(0, 0);

  for (int t = 0; t < nk; t++) {
    const int buf = t & 1;
    __syncthreads();
    if (t + 1 < nk) STAGE(buf ^ 1, (t + 1) << 6);
    const u16* As_ = As[buf];
    const u16* Bs_ = Bs[buf];
#pragma unroll
    for (int h = 0; h < 2; h++) {
      bf16x8 a0 = *reinterpret_cast<const bf16x8*>(As_ + aoff[0][h]);
      bf16x8 a1 = *reinterpret_cast<const bf16x8*>(As_ + aoff[1][h]);
      bf16x8 b0 = *reinterpret_cast<const bf16x8*>(Bs_ + boff[0][h]);
      bf16x8 b1 = *reinterpret_cast<const bf16x8*>(Bs_ + boff[1][h]);
      acc[0][0] = __builtin_amdgcn_mfma_f32_16x16x32_bf16(a0, b0, acc[0][0], 0, 0, 0);
      acc[0][1] = __builtin_amdgcn_mfma_f32_16x16x32_bf16(a0, b1, acc[0][1], 0, 0, 0);
      acc[1][0] = __builtin_amdgcn_mfma_f32_16x16x32_bf16(a1, b0, acc[1][0], 0, 0, 0);
      acc[1][1] = __builtin_amdgcn_mfma_f32_16x16x32_bf16(a1, b1, acc[1][1], 0, 0, 0);
    }
  }
#undef STAGE

#pragma unroll
  for (int i = 0; i < 2; i++) {
#pragma unroll
    for (int j = 0; j < 2; j++) {
      const int col = bn + wn + j * 16 + fr;
      const int row0 = bm + wm + i * 16 + fs * 4;
      float bv = (EPI & 1) ? bias[col] : 0.f;
#pragma unroll
      for (int r = 0; r < 4; r++) {
        float v = acc[i][j][r] + bv;
        if (EPI & 4) v += resid[(size_t)(row0 + r) * ldr + col];
        if (EPI & 16) {
          float z = (EPI & 32)
              ? bf2f(((const u16*)resid)[(size_t)(row0 + r) * ldr + col])
              : resid[(size_t)(row0 + r) * ldr + col];
          v *= z / (1.f + __expf(-z));
        }
        if (EPI & 8) ((u16*)Cv)[(size_t)(row0 + r) * ldc + col] = f2bf(v);
        else         ((float*)Cv)[(size_t)(row0 + r) * ldc + col] = v;
      }
    }
  }
}

// ---------------- fused S + vv GEMM (both consume ypro, K=1536) --------------
__global__ __launch_bounds__(256) void svgemm_k(
    const u16* __restrict__ wA, const u16* __restrict__ ypro,
    const u16* __restrict__ wVT,
    float* __restrict__ Smat, u16* __restrict__ vv)
{
  __shared__ u16 As[2][64 * 64];
  __shared__ u16 Bs[2][64 * 64];
  const int tid = threadIdx.x;
  const int lane = tid & 63;
  const int w = tid >> 6;

  int bid = blockIdx.x;                    // 640 blocks
  bid = (bid & 7) * 80 + (bid >> 3);       // bijective XCD swizzle
  const bool is_s = bid < 256;
  const u16* A;
  const u16* B;
  int bm, bn;
  if (is_s) { A = wA;   B = ypro; bm = (bid >> 4) * 64;         bn = (bid & 15) * 64; }
  else      { A = ypro; B = wVT;  bm = ((bid - 256) / 24) * 64; bn = ((bid - 256) % 24) * 64; }

  const int srow = lane >> 3;
  const int scs = (lane & 7) ^ srow;
  const int gA = 2 * w;
  const u16* Asrc0 = A + (size_t)(bm + gA * 8 + srow) * DINNER + scs * 8;
  const u16* Asrc1 = Asrc0 + (size_t)8 * DINNER;
  const u16* Bsrc0 = B + (size_t)(bn + gA * 8 + srow) * DINNER + scs * 8;
  const u16* Bsrc1 = Bsrc0 + (size_t)8 * DINNER;
  const int d0 = gA * 512;
  const int d1 = d0 + 512;

  const int fr = lane & 15;
  const int fs = lane >> 4;
  const int wm = (w >> 1) * 32;
  const int wn = (w & 1) * 32;
  int aoff[2][2], boff[2][2];
#pragma unroll
  for (int i = 0; i < 2; i++)
#pragma unroll
    for (int h = 0; h < 2; h++) {
      const int g = h * 4 + fs;
      aoff[i][h] = (wm + i * 16 + fr) * 64 + (g ^ (fr & 7)) * 8;
      boff[i][h] = (wn + i * 16 + fr) * 64 + (g ^ (fr & 7)) * 8;
    }

  f32x4 acc[2][2];
#pragma unroll
  for (int i = 0; i < 2; i++)
#pragma unroll
    for (int j = 0; j < 2; j++) acc[i][j] = (f32x4){0.f, 0.f, 0.f, 0.f};

#define STAGE(buf, k0) do { \
    gload16(Asrc0 + (k0), &As[buf][d0]); \
    gload16(Asrc1 + (k0), &As[buf][d1]); \
    gload16(Bsrc0 + (k0), &Bs[buf][d0]); \
    gload16(Bsrc1 + (k0), &Bs[buf][d1]); \
  } while (0)

  STAGE(0, 0);
  for (int t = 0; t < DINNER / 64; t++) {
    const int buf = t & 1;
    __syncthreads();
    if (t + 1 < DINNER / 64) STAGE(buf ^ 1, (t + 1) << 6);
    const u16* As_ = As[buf];
    const u16* Bs_ = Bs[buf];
#pragma unroll
    for (int h = 0; h < 2; h++) {
      bf16x8 a0 = *reinterpret_cast<const bf16x8*>(As_ + aoff[0][h]);
      bf16x8 a1 = *reinterpret_cast<const bf16x8*>(As_ + aoff[1][h]);
      bf16x8 b0 = *reinterpret_cast<const bf16x8*>(Bs_ + boff[0][h]);
      bf16x8 b1 = *reinterpret_cast<const bf16x8*>(Bs_ + boff[1][h]);
      acc[0][0] = __builtin_amdgcn_mfma_f32_16x16x32_bf16(a0, b0, acc[0][0], 0, 0, 0);
      acc[0][1] = __builtin_amdgcn_mfma_f32_16x16x32_bf16(a0, b1, acc[0][1], 0, 0, 0);
      acc[1][0] = __builtin_amdgcn_mfma_f32_16x16x32_bf16(a1, b0, acc[1][0], 0, 0, 0);
      acc[1][1] = __builtin_amdgcn_mfma_f32_16x16x32_bf16(a1, b1, acc[1][1], 0, 0, 0);
    }
  }
#undef STAGE

#pragma unroll
  for (int i = 0; i < 2; i++) {
#pragma unroll
    for (int j = 0; j < 2; j++) {
      const int col = bn + wn + j * 16 + fr;
      const int row0 = bm + wm + i * 16 + fs * 4;
#pragma unroll
      for (int r = 0; r < 4; r++) {
        float v = acc[i][j][r];
        if (is_s) Smat[(size_t)(row0 + r) * LSEQ + col] = v;
        else      vv[(size_t)(row0 + r) * DINNER + col] = f2bf(v);
      }
    }
  }
}

// ---------------- thin dbc GEMM (bf16 A, f+b merged) -------------------------
#define TG_R 16
#define TG_KC 96
#define TG_KS 16

__global__ __launch_bounds__(256) void thin_gemm_k(
    const u16* __restrict__ Af_, const u16* __restrict__ Ab_,   // [1024][1536] bf16
    const float* __restrict__ Bf_, const float* __restrict__ Bb_,
    float* __restrict__ partial)
{
  __shared__ u16 As[TG_R][TG_KC];
  __shared__ float Bs[80][100];
  const u16* A = blockIdx.z ? Ab_ : Af_;
  const float* B = blockIdx.z ? Bb_ : Bf_;
  float* part = partial + (size_t)blockIdx.z * TG_KS * LSEQ * DBC;
  const int tid = threadIdx.x;
  const int m0 = blockIdx.x * TG_R;
  const int ks = blockIdx.y;
  const int k0 = ks * TG_KC;

  // BUGFIX (r12): us4 = 4 u16 (8 B), so 16x96 u16 needs 384 copies at stride 4
  for (int i = tid; i < 384; i += 256) {
    int r = i / 24, q = i % 24;
    *(us4*)&As[r][q * 4] = *(const us4*)(A + (size_t)(m0 + r) * DINNER + k0 + q * 4);
  }
  for (int i = tid; i < 1920; i += 256) {  // B tile: 80 x 96 fp32
    int r = i / 24, q = i % 24;
    *(float4*)&Bs[r][q * 4] = *(const float4*)(B + (size_t)r * DINNER + k0 + q * 4);
  }
  __syncthreads();

  const int r = tid >> 4;
  const int c0 = (tid & 15) * 5;
  float acc[5] = {};
  for (int k = 0; k < TG_KC; k++) {
    float a = bf2f(As[r][k]);
#pragma unroll
    for (int j = 0; j < 5; j++) acc[j] += a * Bs[c0 + j][k];
  }
  float* out = part + ((size_t)ks * LSEQ + m0 + r) * DBC + c0;
#pragma unroll
  for (int j = 0; j < 5; j++) out[j] = acc[j];
}

__global__ __launch_bounds__(256) void reduce_dbc_k(const float* __restrict__ partial,
                                                    float* __restrict__ outf,
                                                    float* __restrict__ outb) {
  int i = blockIdx.x * 256 + threadIdx.x;
  const float* part = partial + (size_t)blockIdx.y * TG_KS * LSEQ * DBC;
  float s = 0.f;
#pragma unroll
  for (int ks = 0; ks < TG_KS; ks++) s += part[(size_t)ks * (LSEQ * DBC) + i];
  (blockIdx.y ? outb : outf)[i] = s;
}

// ---------------- delta = softplus(dlt @ dt_w^T + dt_b), f+b merged, bf16 out
#define BM 64
#define BN 64
#define BK 16

__global__ __launch_bounds__(256) void delta_gemm_k(
    const float* __restrict__ A0, const float* __restrict__ A1,
    const float* __restrict__ B0, const float* __restrict__ B1,
    const float* __restrict__ b0, const float* __restrict__ b1,
    u16* __restrict__ C0, u16* __restrict__ C1)
{
  __shared__ float Asf[BK][BM];
  __shared__ float Bsf[BK][BN + 4];
  const float* A = blockIdx.z ? A1 : A0;
  const float* B = blockIdx.z ? B1 : B0;
  const float* bias = blockIdx.z ? b1 : b0;
  u16* C = blockIdx.z ? C1 : C0;
  const int tid = threadIdx.x;
  const int bm = blockIdx.y * BM;
  const int bn = blockIdx.x * BN;
  const int ar = tid >> 2;
  const int ak = (tid & 3) << 2;
  const int ty = tid >> 4, tx = tid & 15;
  float acc[4][4] = {};

  for (int k0 = 0; k0 < DRANK; k0 += BK) {
    float4 av = *(const float4*)(A + (size_t)(bm + ar) * DBC + k0 + ak);
    float4 bv = *(const float4*)(B + (size_t)(bn + ar) * DRANK + k0 + ak);
    __syncthreads();
    Asf[ak + 0][ar] = av.x; Asf[ak + 1][ar] = av.y;
    Asf[ak + 2][ar] = av.z; Asf[ak + 3][ar] = av.w;
    Bsf[ak + 0][ar] = bv.x; Bsf[ak + 1][ar] = bv.y;
    Bsf[ak + 2][ar] = bv.z; Bsf[ak + 3][ar] = bv.w;
    __syncthreads();
#pragma unroll
    for (int kk = 0; kk < BK; kk++) {
      float4 a4 = *(const float4*)&Asf[kk][ty * 4];
      float4 b4 = *(const float4*)&Bsf[kk][tx * 4];
      float a[4] = {a4.x, a4.y, a4.z, a4.w};
      float b[4] = {b4.x, b4.y, b4.z, b4.w};
#pragma unroll
      for (int i = 0; i < 4; i++)
#pragma unroll
        for (int j = 0; j < 4; j++)
          acc[i][j] += a[i] * b[j];
    }
  }

#pragma unroll
  for (int i = 0; i < 4; i++) {
    int row = bm + ty * 4 + i;
#pragma unroll
    for (int j = 0; j < 4; j++) {
      int col = bn + tx * 4 + j;
      float v = acc[i][j] + bias[col];
      v = (v > 20.f) ? v : log1pf(__expf(v));
      C[(size_t)row * DINNER + col] = f2bf(v);
    }
  }
}

// ---------------- causal depthwise conv + silu (bf16 in/out, both dirs) ------
__global__ __launch_bounds__(256) void conv_silu_k(
    const u16* __restrict__ xz,
    const float* __restrict__ wf, const float* __restrict__ bf,
    const float* __restrict__ wb, const float* __restrict__ bb,
    u16* __restrict__ xf, u16* __restrict__ xb)
{
  int idx = blockIdx.x * 256 + threadIdx.x;
  int dir = blockIdx.y;
  if (idx >= LSEQ * DINNER) return;
  int l = idx / DINNER, c = idx % DINNER;
  const float* w = (dir ? wb : wf) + c * KCONV;
  float acc = (dir ? bb : bf)[c];
#pragma unroll
  for (int k = 0; k < KCONV; k++) {
    int ls = l - (KCONV - 1) + k;
    if (ls >= 0) {
      int lsrc = dir ? (LSEQ - 1 - ls) : ls;
      acc += w[k] * bf2f(xz[(size_t)lsrc * (2 * DINNER) + c]);
    }
  }
  float sv = acc / (1.f + __expf(-acc));
  (dir ? xb : xf)[idx] = f2bf(sv);
}

// ---------------- 3-phase L-split scan: 8 chunks x 32 channels (bf16 in) -----
__global__ __launch_bounds__(256) void scan_a_k(
    const u16* __restrict__ xcf, const u16* __restrict__ xcb,
    const u16* __restrict__ dltf, const u16* __restrict__ dltb,
    const float* __restrict__ dbcf, const float* __restrict__ dbcb,
    const float* __restrict__ Af, const float* __restrict__ Ab,
    float* __restrict__ qsP, float* __restrict__ qsQ)  // [2][NQ][DINNER][16]
{
  __shared__ float sP[SCH * SCW * DSTATE];  // 16 KB
  __shared__ float sQ[SCH * SCW * DSTATE];
  const int dir = blockIdx.z;
  const int qid = blockIdx.y;
  const u16*   xc    = dir ? xcb : xcf;
  const u16*   delta = dir ? dltb : dltf;
  const float* dbc   = dir ? dbcb : dbcf;
  const float* A_log = dir ? Ab : Af;

  const int tid = threadIdx.x;
  const int c = tid >> 5;       // chunk 0..7
  const int dl = tid & 31;      // channel 0..31 (full cacheline)
  const int d = blockIdx.x * SCW + dl;

  float Aa[DSTATE];
#pragma unroll
  for (int s = 0; s < DSTATE; s++) Aa[s] = -__expf(A_log[(size_t)d * DSTATE + s]);

  float aP[DSTATE], q[DSTATE];
#pragma unroll
  for (int s = 0; s < DSTATE; s++) { aP[s] = 1.f; q[s] = 0.f; }
  const int l0 = qid * QL + c * QCH;
  for (int i = 0; i < QCH; i++) {
    int l = l0 + i;
    float dt = bf2f(delta[(size_t)l * DINNER + d]);
    float dx = dt * bf2f(xc[(size_t)l * DINNER + d]);
    const float* bm = dbc + (size_t)l * DBC + DRANK;
#pragma unroll
    for (int s = 0; s < DSTATE; s++) {
      float a = __expf(dt * Aa[s]);
      q[s] = a * q[s] + dx * bm[s];
      aP[s] *= a;
    }
  }
#pragma unroll
  for (int s = 0; s < DSTATE; s++) {
    sP[(c * SCW + dl) * DSTATE + s] = aP[s];
    sQ[(c * SCW + dl) * DSTATE + s] = q[s];
  }
  __syncthreads();

  // phase 2: 512 (d,s) pairs over 256 threads
#pragma unroll
  for (int pp = 0; pp < 2; pp++) {
    const int p = tid + pp * 256;
    const int d2 = p >> 4, s2 = p & 15;
    float h = 0.f, P = 1.f;
    for (int cc = 0; cc < SCH; cc++) {
      int idx = (cc * SCW + d2) * DSTATE + s2;
      h = sP[idx] * h + sQ[idx];
      P *= sP[idx];
    }
    size_t o = (((size_t)dir * NQ + qid) * DINNER + blockIdx.x * SCW + d2) * DSTATE + s2;
    qsP[o] = P;
    qsQ[o] = h;
  }
}

__global__ __launch_bounds__(256) void scan_c_k(
    const u16* __restrict__ xcf, const u16* __restrict__ xcb,
    const u16* __restrict__ dltf, const u16* __restrict__ dltb,
    const float* __restrict__ dbcf, const float* __restrict__ dbcb,
    const float* __restrict__ Af, const float* __restrict__ Ab,
    const float* __restrict__ Df, const float* __restrict__ Db,
    const float* __restrict__ qsP, const float* __restrict__ qsQ,
    u16* __restrict__ ycat)
{
  __shared__ float sP[SCH * SCW * DSTATE];
  __shared__ float sQ[SCH * SCW * DSTATE];
  const int dir = blockIdx.z;
  const int qid = blockIdx.y;
  const u16*   xc    = dir ? xcb : xcf;
  const u16*   delta = dir ? dltb : dltf;
  const float* dbc   = dir ? dbcb : dbcf;
  const float* A_log = dir ? Ab : Af;
  const float* Dvec  = dir ? Db : Df;
  const int col_off  = dir ? DINNER : 0;

  const int tid = threadIdx.x;
  const int c = tid >> 5;
  const int dl = tid & 31;
  const int d = blockIdx.x * SCW + dl;

  float Aa[DSTATE];
#pragma unroll
  for (int s = 0; s < DSTATE; s++) Aa[s] = -__expf(A_log[(size_t)d * DSTATE + s]);

  float aP[DSTATE], q[DSTATE];
#pragma unroll
  for (int s = 0; s < DSTATE; s++) { aP[s] = 1.f; q[s] = 0.f; }
  const int l0 = qid * QL + c * QCH;
  for (int i = 0; i < QCH; i++) {
    int l = l0 + i;
    float dt = bf2f(delta[(size_t)l * DINNER + d]);
    float dx = dt * bf2f(xc[(size_t)l * DINNER + d]);
    const float* bm = dbc + (size_t)l * DBC + DRANK;
#pragma unroll
    for (int s = 0; s < DSTATE; s++) {
      float a = __expf(dt * Aa[s]);
      q[s] = a * q[s] + dx * bm[s];
      aP[s] *= a;
    }
  }
#pragma unroll
  for (int s = 0; s < DSTATE; s++) {
    sP[(c * SCW + dl) * DSTATE + s] = aP[s];
    sQ[(c * SCW + dl) * DSTATE + s] = q[s];
  }
  __syncthreads();

  // phase 2 with inline quarter-carry (combine qq < qid, <=7 steps)
#pragma unroll
  for (int pp = 0; pp < 2; pp++) {
    const int p = tid + pp * 256;
    const int d2 = p >> 4, s2 = p & 15;
    float h = 0.f;
    for (int qq = 0; qq < qid; qq++) {
      size_t o = (((size_t)dir * NQ + qq) * DINNER + blockIdx.x * SCW + d2) * DSTATE + s2;
      h = qsP[o] * h + qsQ[o];
    }
    for (int cc = 0; cc < SCH; cc++) {
      int idx = (cc * SCW + d2) * DSTATE + s2;
      float a = sP[idx], qv = sQ[idx];
      sP[idx] = h;
      h = a * h + qv;
    }
  }
  __syncthreads();

  float hs[DSTATE];
#pragma unroll
  for (int s = 0; s < DSTATE; s++) hs[s] = sP[(c * SCW + dl) * DSTATE + s];
  const float Dd = Dvec[d];
  for (int i = 0; i < QCH; i++) {
    int l = l0 + i;
    float dt = bf2f(delta[(size_t)l * DINNER + d]);
    float xv = bf2f(xc[(size_t)l * DINNER + d]);
    float dx = dt * xv;
    const float* bm = dbc + (size_t)l * DBC + DRANK;
    const float* cm = bm + DSTATE;
    float y = 0.f;
#pragma unroll
    for (int s = 0; s < DSTATE; s++) {
      float a = __expf(dt * Aa[s]);
      hs[s] = a * hs[s] + dx * bm[s];
      y += hs[s] * cm[s];
    }
    ycat[(size_t)l * (2 * DINNER) + col_off + d] = f2bf(y + Dd * xv);
  }
}

// ---------------- row softmax (fp32 in, bf16 out) ----------------
__global__ __launch_bounds__(256) void softmax_k(const float* __restrict__ S,
                                                 u16* __restrict__ P) {
  int row = blockIdx.x, tid = threadIdx.x;
  __shared__ float buf[LSEQ];
  __shared__ float red[256];
  const float* r = S + (size_t)row * LSEQ;
  float m = -1e30f;
  for (int j = tid; j < LSEQ; j += 256) { float v = r[j]; buf[j] = v; m = fmaxf(m, v); }
  red[tid] = m; __syncthreads();
  for (int s = 128; s > 0; s >>= 1) { if (tid < s) red[tid] = fmaxf(red[tid], red[tid + s]); __syncthreads(); }
  m = red[0];
  __syncthreads();
  float sum = 0.f;
  for (int j = tid; j < LSEQ; j += 256) { float e = __expf(buf[j] - m); buf[j] = e; sum += e; }
  red[tid] = sum; __syncthreads();
  for (int s = 128; s > 0; s >>= 1) { if (tid < s) red[tid] += red[tid + s]; __syncthreads(); }
  float inv = 1.f / red[0];
  u16* pr = P + (size_t)row * LSEQ;
  for (int j = tid; j < LSEQ; j += 256) pr[j] = f2bf(buf[j] * inv);
}

extern "C" void kernel_launch(void* const* d_in, const int* in_sizes, int n_in,
                              void* d_out, int out_size, void* d_ws, size_t ws_size,
                              hipStream_t stream) {
  const float* in_x      = (const float*)d_in[0];
  const float* norm_w    = (const float*)d_in[1];
  const float* in_proj_w = (const float*)d_in[2];
  const float* conv_f_w  = (const float*)d_in[3];
  const float* conv_f_b  = (const float*)d_in[4];
  const float* conv_b_w  = (const float*)d_in[5];
  const float* conv_b_b  = (const float*)d_in[6];
  const float* xproj_f_w = (const float*)d_in[7];
  const float* xproj_b_w = (const float*)d_in[8];
  const float* dt_f_w    = (const float*)d_in[9];
  const float* dt_f_b    = (const float*)d_in[10];
  const float* dt_b_w    = (const float*)d_in[11];
  const float* dt_b_b    = (const float*)d_in[12];
  const float* A_log_f   = (const float*)d_in[13];
  const float* D_f       = (const float*)d_in[14];
  const float* A_log_b   = (const float*)d_in[15];
  const float* D_b       = (const float*)d_in[16];
  const float* out_w     = (const float*)d_in[17];
  const float* token_wA  = (const float*)d_in[18];
  const float* token_wV  = (const float*)d_in[19];
  const float* pro_w     = (const float*)d_in[20];
  const float* pro_b     = (const float*)d_in[21];

  // ---- workspace carve (fp32 units) ----
  float* ws = (float*)d_ws;
  float* xbuf = ws; ws += LSEQ * DMODEL;
  u16* xz_bf  = (u16*)ws; ws += LSEQ * DINNER;        // [L][2*DINNER] u16
  u16* xf_bf  = (u16*)ws; ws += (LSEQ * DINNER) / 2;  // [L][DINNER] u16
  u16* xb_bf  = (u16*)ws; ws += (LSEQ * DINNER) / 2;
  float* dbcf = ws; ws += LSEQ * DBC;
  float* dbcb = ws; ws += LSEQ * DBC;
  float* delf_r = ws; ws += LSEQ * DINNER;  // region: dbc partials; bf16 delta; Smat
  float* delb_r = ws; ws += LSEQ * DINNER;
  float* scr  = ws; ws += LSEQ * DINNER;    // scan quarter summaries
  u16* xn_bf   = (u16*)ws; ws += (LSEQ * DMODEL) / 2;
  u16* ycat_bf = (u16*)ws; ws += LSEQ * DINNER;
  u16* ypro_bf = (u16*)ws; ws += (LSEQ * DINNER) / 2;
  u16* Wb      = (u16*)ws;
  u16* in_w_bf = Wb;
  u16* pw_bf   = in_w_bf + 3072 * 768;
  u16* wA_bf   = pw_bf + 1536 * 3072;
  u16* wVT_bf  = wA_bf + 1024 * 1536;
  u16* ow_bf   = wVT_bf + 1536 * 1536;

  // aliases (verified live ranges)
  float* dbc_part = delf_r;       // [2][16][1024][80] = 2.62M <= delf_r+delb_r
  u16*   delf_bf  = (u16*)delf_r; // bf16 delta written after partials reduced
  u16*   delb_bf  = (u16*)delb_r;
  float* Smat     = delf_r;       // written after scans consume delta
  u16*   Smat_bf  = (u16*)delb_r;
  u16*   vv_bf    = xf_bf;        // xf dead after scan_c
  u16*   vvT_bf   = xb_bf;        // xb dead after scan_c
  u16*   g_bf     = ypro_bf;      // ypro last read by fused S+vv gemm
  const int QS = 2 * NQ * DINNER * DSTATE;  // 393216
  float* qsP   = scr;
  float* qsQ   = scr + QS;        // 2*QS = 786432 < LSEQ*DINNER

  dim3 blk(256);
  for (int layer = 0; layer < NLAYER; layer++) {
    const float* nw  = norm_w    + (size_t)layer * DMODEL;
    const float* iw  = in_proj_w + (size_t)layer * 2 * DINNER * DMODEL;
    const float* cfw = conv_f_w  + (size_t)layer * DINNER * KCONV;
    const float* cfb = conv_f_b  + (size_t)layer * DINNER;
    const float* cbw = conv_b_w  + (size_t)layer * DINNER * KCONV;
    const float* cbb = conv_b_b  + (size_t)layer * DINNER;
    const float* xfw = xproj_f_w + (size_t)layer * DBC * DINNER;
    const float* xbw = xproj_b_w + (size_t)layer * DBC * DINNER;
    const float* dfw = dt_f_w    + (size_t)layer * DINNER * DRANK;
    const float* dfb = dt_f_b    + (size_t)layer * DINNER;
    const float* dbw = dt_b_w    + (size_t)layer * DINNER * DRANK;
    const float* dbb = dt_b_b    + (size_t)layer * DINNER;
    const float* Af  = A_log_f   + (size_t)layer * DINNER * DSTATE;
    const float* Df  = D_f       + (size_t)layer * DINNER;
    const float* Ab  = A_log_b   + (size_t)layer * DINNER * DSTATE;
    const float* Db  = D_b       + (size_t)layer * DINNER;
    const float* ow  = out_w     + (size_t)layer * DMODEL * DINNER;
    const float* wA  = token_wA  + (size_t)layer * LSEQ * DINNER;
    const float* wV  = token_wV  + (size_t)layer * DINNER * DINNER;
    const float* pw  = pro_w     + (size_t)layer * DINNER * 2 * DINNER;
    const float* pb  = pro_b     + (size_t)layer * DINNER;

    const float* xsrc = (layer == 0) ? in_x : xbuf;   // residual stream source

    // weight conversions (one fused dispatch + wV transpose)
    cvt4_k<<<CV3 / 256, blk, 0, stream>>>(iw, in_w_bf, pw, pw_bf, wA, wA_bf, ow, ow_bf);
    transcvt_k<<<dim3(1536 / 32, 1536 / 32), blk, 0, stream>>>(wV, wVT_bf, 1536, 1536);

    rmsnorm_k<<<LSEQ, blk, 0, stream>>>(xsrc, nw, xn_bf);

    // xz = xn @ in_w^T   [1024,3072] k=768 -> bf16
    mgemm_k<8><<<dim3(3072 / 64, LSEQ / 64), blk, 0, stream>>>(
        xn_bf, DMODEL, in_w_bf, DMODEL, xz_bf, 2 * DINNER, DMODEL, nullptr, nullptr, 0);

    conv_silu_k<<<dim3((LSEQ * DINNER) / 256, 2), blk, 0, stream>>>(
        xz_bf, cfw, cfb, cbw, cbb, xf_bf, xb_bf);

    // dbc = x @ xproj^T  [1024,80] k=1536 (bf16 A, fp32 acc)
    thin_gemm_k<<<dim3(LSEQ / TG_R, TG_KS, 2), blk, 0, stream>>>(
        xf_bf, xb_bf, xfw, xbw, dbc_part);
    reduce_dbc_k<<<dim3((LSEQ * DBC) / 256, 2), blk, 0, stream>>>(
        dbc_part, dbcf, dbcb);

    // delta = softplus(dlt @ dt_w^T + dt_b) -> bf16
    delta_gemm_k<<<dim3(DINNER / BN, LSEQ / BM, 2), blk, 0, stream>>>(
        dbcf, dbcb, dfw, dbw, dfb, dbb, delf_bf, delb_bf);

    // 3-phase scan: grid (48,8,2) = 768 blocks, full-cacheline reads
    scan_a_k<<<dim3(DINNER / SCW, NQ, 2), blk, 0, stream>>>(
        xf_bf, xb_bf, delf_bf, delb_bf, dbcf, dbcb, Af, Ab, qsP, qsQ);
    scan_c_k<<<dim3(DINNER / SCW, NQ, 2), blk, 0, stream>>>(
        xf_bf, xb_bf, delf_bf, delb_bf, dbcf, dbcb, Af, Ab, Df, Db, qsP, qsQ, ycat_bf);

    // ypro = ycat @ pro_w^T + pro_b   [1024,1536] k=3072 -> bf16
    mgemm_k<9><<<dim3(DINNER / 64, LSEQ / 64), blk, 0, stream>>>(
        ycat_bf, 2 * DINNER, pw_bf, 2 * DINNER, ypro_bf, DINNER, 2 * DINNER,
        pb, nullptr, 0);

    // fused: S = wA.ypro^T (fp32) and vv = ypro.wV (bf16)
    svgemm_k<<<640, blk, 0, stream>>>(wA_bf, ypro_bf, wVT_bf, Smat, vv_bf);
    softmax_k<<<LSEQ, blk, 0, stream>>>(Smat, Smat_bf);

    // vvT[e][l] = vv[l][e]
    transpose16_k<<<dim3(DINNER / 32, LSEQ / 32), blk, 0, stream>>>(
        vv_bf, vvT_bf, LSEQ, DINNER);

    // g = (att @ vv) * silu(z)  -> bf16 (z read as bf16 from xz)
    mgemm_k<56><<<dim3(DINNER / 64, LSEQ / 64), blk, 0, stream>>>(
        Smat_bf, LSEQ, vvT_bf, LSEQ, g_bf, DINNER, LSEQ,
        nullptr, (const float*)(xz_bf + DINNER), 2 * DINNER);

    // x_next = x + g @ out_w^T   [1024,768] k=1536
    float* target = (layer == NLAYER - 1) ? (float*)d_out : xbuf;
    mgemm_k<4><<<dim3(DMODEL / 64, LSEQ / 64), blk, 0, stream>>>(
        g_bf, DINNER, ow_bf, DINNER, target, DMODEL, DINNER,
        nullptr, xsrc, DMODEL);
  }
}